// Round 1
// baseline (757.364 us; speedup 1.0000x reference)
//
#include <hip/hip_runtime.h>
#include <hip/hip_bf16.h>
#include <math.h>

#define HCOLS 256          // H * C = 4 * 64, hidden width for all layers
#define NHEAD 4
#define CDIM  64
#define NEG_SLOPE 0.2f

// ---------------------------------------------------------------- CSR build
__global__ void deg_kernel(const int* __restrict__ ei, int* __restrict__ deg,
                           int E, int Ep) {
    int e = blockIdx.x * 256 + threadIdx.x;
    if (e >= Ep) return;
    int d = (e < E) ? ei[E + e] : (e - E);
    atomicAdd(&deg[d], 1);
}

__global__ void scan_kernel(const int* __restrict__ deg, int* __restrict__ rowptr,
                            int* __restrict__ cursor, int n) {
    __shared__ int tmp[1024];
    __shared__ int carry_s;
    int tid = threadIdx.x;
    if (tid == 0) carry_s = 0;
    __syncthreads();
    for (int base = 0; base < n; base += 1024) {
        int i = base + tid;
        int v = (i < n) ? deg[i] : 0;
        tmp[tid] = v;
        __syncthreads();
        for (int off = 1; off < 1024; off <<= 1) {
            int t = (tid >= off) ? tmp[tid - off] : 0;
            __syncthreads();
            tmp[tid] += t;
            __syncthreads();
        }
        int excl = carry_s + tmp[tid] - v;   // read carry before update
        if (i < n) { rowptr[i] = excl; cursor[i] = excl; }
        __syncthreads();
        if (tid == 1023) carry_s += tmp[1023];
        __syncthreads();
    }
    if (tid == 0) rowptr[n] = carry_s;
}

__global__ void fill_kernel(const int* __restrict__ ei, int* __restrict__ cursor,
                            int* __restrict__ eidx, int E, int Ep) {
    int e = blockIdx.x * 256 + threadIdx.x;
    if (e >= Ep) return;
    int d = (e < E) ? ei[E + e] : (e - E);
    int pos = atomicAdd(&cursor[d], 1);
    eidx[pos] = e;
}

// ---------------------------------------------------------------- GEMM  h = X @ W
// block: 256 threads -> 16 rows x 256 cols. X rows staged in LDS.
template <int K>
__global__ void gemm_kernel(const float* __restrict__ X, const float* __restrict__ W,
                            float* __restrict__ Hout, int n) {
    __shared__ __align__(16) float xs[16][K];
    int row0 = blockIdx.x * 16;
    int tid = threadIdx.x;
    for (int idx = tid; idx < 16 * K; idx += 256) {
        int r = idx / K, k = idx % K;
        int row = row0 + r;
        xs[r][k] = (row < n) ? X[(size_t)row * K + k] : 0.f;
    }
    __syncthreads();
    float acc[16];
#pragma unroll
    for (int r = 0; r < 16; ++r) acc[r] = 0.f;
    for (int k = 0; k < K; k += 4) {
        float w0 = W[(k + 0) * HCOLS + tid];
        float w1 = W[(k + 1) * HCOLS + tid];
        float w2 = W[(k + 2) * HCOLS + tid];
        float w3 = W[(k + 3) * HCOLS + tid];
#pragma unroll
        for (int r = 0; r < 16; ++r) {
            float4 xv = *reinterpret_cast<const float4*>(&xs[r][k]);
            acc[r] = fmaf(xv.x, w0, acc[r]);
            acc[r] = fmaf(xv.y, w1, acc[r]);
            acc[r] = fmaf(xv.z, w2, acc[r]);
            acc[r] = fmaf(xv.w, w3, acc[r]);
        }
    }
#pragma unroll
    for (int r = 0; r < 16; ++r) {
        int row = row0 + r;
        if (row < n) Hout[(size_t)row * HCOLS + tid] = acc[r];
    }
}

// ---------------------------------------------------------------- per-node attn coefs
// block = 1 node, 256 threads; wave w (64 lanes) reduces head w.
__global__ void edge_coef_kernel(const float* __restrict__ h, const float* __restrict__ a_s,
                                 const float* __restrict__ a_d, float* __restrict__ esrc,
                                 float* __restrict__ edst) {
    int node = blockIdx.x;
    int t = threadIdx.x;
    float v = h[(size_t)node * HCOLS + t];
    float ps = v * a_s[t];
    float pd = v * a_d[t];
    for (int off = 32; off > 0; off >>= 1) {
        ps += __shfl_down(ps, off, 64);
        pd += __shfl_down(pd, off, 64);
    }
    if ((t & 63) == 0) {
        int head = t >> 6;
        esrc[node * NHEAD + head] = ps;
        edst[node * NHEAD + head] = pd;
    }
}

// ---------------------------------------------------------------- segment softmax
// one thread per (node, head): 3 passes over this node's in-edges.
__global__ void attn_kernel(const int* __restrict__ ei, const int* __restrict__ rowptr,
                            const int* __restrict__ eidx, const float* __restrict__ esrc,
                            const float* __restrict__ edst, float* __restrict__ alpha,
                            int n, int E) {
    int t = blockIdx.x * 256 + threadIdx.x;
    if (t >= n * NHEAD) return;
    int node = t >> 2;
    int head = t & 3;
    int s0 = rowptr[node], s1 = rowptr[node + 1];
    float ed = edst[node * NHEAD + head];
    float m = -3.4e38f;
    for (int i = s0; i < s1; ++i) {
        int e = eidx[i];
        int s = (e < E) ? ei[e] : (e - E);
        float lg = esrc[s * NHEAD + head] + ed;
        lg = (lg > 0.f) ? lg : lg * NEG_SLOPE;
        m = fmaxf(m, lg);
    }
    float denom = 0.f;
    for (int i = s0; i < s1; ++i) {
        int e = eidx[i];
        int s = (e < E) ? ei[e] : (e - E);
        float lg = esrc[s * NHEAD + head] + ed;
        lg = (lg > 0.f) ? lg : lg * NEG_SLOPE;
        denom += __expf(lg - m);
    }
    float inv = 1.f / denom;
    for (int i = s0; i < s1; ++i) {
        int e = eidx[i];
        int s = (e < E) ? ei[e] : (e - E);
        float lg = esrc[s * NHEAD + head] + ed;
        lg = (lg > 0.f) ? lg : lg * NEG_SLOPE;
        alpha[(size_t)e * NHEAD + head] = __expf(lg - m) * inv;
    }
}

// ---------------------------------------------------------------- aggregation
// block = 1 node, wave = 1 head, lane = channel. Fused bias + ELU.
__global__ void aggregate_kernel(const float* __restrict__ h, const float* __restrict__ alpha,
                                 const int* __restrict__ ei, const int* __restrict__ rowptr,
                                 const int* __restrict__ eidx, const float* __restrict__ bias,
                                 float* __restrict__ xout, int E) {
    int node = blockIdx.x;
    int head = threadIdx.x >> 6;
    int lane = threadIdx.x & 63;
    int s0 = rowptr[node], s1 = rowptr[node + 1];
    float acc = 0.f;
    for (int i = s0; i < s1; ++i) {
        int e = eidx[i];
        int s = (e < E) ? ei[e] : (e - E);
        float a = alpha[(size_t)e * NHEAD + head];
        acc = fmaf(a, h[(size_t)s * HCOLS + head * CDIM + lane], acc);
    }
    float v = acc + bias[head * CDIM + lane];
    v = (v > 0.f) ? v : expm1f(v);           // ELU
    xout[(size_t)node * HCOLS + head * CDIM + lane] = v;
}

// last layer: mean over heads, + bias, C_OUT = 64
__global__ void aggregate_mean_kernel(const float* __restrict__ h, const float* __restrict__ alpha,
                                      const int* __restrict__ ei, const int* __restrict__ rowptr,
                                      const int* __restrict__ eidx, const float* __restrict__ bias,
                                      float* __restrict__ out, int E) {
    __shared__ float accs[NHEAD][CDIM];
    int node = blockIdx.x;
    int head = threadIdx.x >> 6;
    int lane = threadIdx.x & 63;
    int s0 = rowptr[node], s1 = rowptr[node + 1];
    float acc = 0.f;
    for (int i = s0; i < s1; ++i) {
        int e = eidx[i];
        int s = (e < E) ? ei[e] : (e - E);
        float a = alpha[(size_t)e * NHEAD + head];
        acc = fmaf(a, h[(size_t)s * HCOLS + head * CDIM + lane], acc);
    }
    accs[head][lane] = acc;
    __syncthreads();
    if (head == 0) {
        float v = (accs[0][lane] + accs[1][lane] + accs[2][lane] + accs[3][lane]) * 0.25f
                  + bias[lane];
        out[(size_t)node * CDIM + lane] = v;
    }
}

// ---------------------------------------------------------------- launch
extern "C" void kernel_launch(void* const* d_in, const int* in_sizes, int n_in,
                              void* d_out, int out_size, void* d_ws, size_t ws_size,
                              hipStream_t stream) {
    const float* x   = (const float*)d_in[0];
    const int*   ei  = (const int*)d_in[1];
    const float* W0  = (const float*)d_in[2];
    const float* as0 = (const float*)d_in[3];
    const float* ad0 = (const float*)d_in[4];
    const float* b0  = (const float*)d_in[5];
    const float* W1  = (const float*)d_in[6];
    const float* as1 = (const float*)d_in[7];
    const float* ad1 = (const float*)d_in[8];
    const float* b1  = (const float*)d_in[9];
    const float* W2  = (const float*)d_in[10];
    const float* as2 = (const float*)d_in[11];
    const float* ad2 = (const float*)d_in[12];
    const float* b2  = (const float*)d_in[13];

    const int N  = in_sizes[0] / 128;
    const int E  = in_sizes[1] / 2;
    const int Ep = E + N;

    float* out = (float*)d_out;
    float* a0  = out + (size_t)N * CDIM;
    float* a1  = a0 + (size_t)Ep * NHEAD;
    float* a2  = a1 + (size_t)Ep * NHEAD;

    char* wp = (char*)d_ws;
    auto carve = [&](size_t bytes) {
        char* p = wp;
        wp += (bytes + 255) & ~(size_t)255;
        return (void*)p;
    };
    float* hbuf   = (float*)carve((size_t)N * HCOLS * 4);
    float* xbuf   = (float*)carve((size_t)N * HCOLS * 4);
    float* esrc   = (float*)carve((size_t)N * NHEAD * 4);
    float* edst   = (float*)carve((size_t)N * NHEAD * 4);
    int*   deg    = (int*)carve((size_t)N * 4);
    int*   rowptr = (int*)carve((size_t)(N + 1) * 4);
    int*   cursor = (int*)carve((size_t)N * 4);
    int*   eidx   = (int*)carve((size_t)Ep * 4);

    // CSR by dst (graph identical for all layers)
    hipMemsetAsync(deg, 0, (size_t)N * 4, stream);
    deg_kernel<<<(Ep + 255) / 256, 256, 0, stream>>>(ei, deg, E, Ep);
    scan_kernel<<<1, 1024, 0, stream>>>(deg, rowptr, cursor, N);
    fill_kernel<<<(Ep + 255) / 256, 256, 0, stream>>>(ei, cursor, eidx, E, Ep);

    int attn_grid = (N * NHEAD + 255) / 256;

    // ---- layer 0 (K = 128)
    gemm_kernel<128><<<(N + 15) / 16, 256, 0, stream>>>(x, W0, hbuf, N);
    edge_coef_kernel<<<N, 256, 0, stream>>>(hbuf, as0, ad0, esrc, edst);
    attn_kernel<<<attn_grid, 256, 0, stream>>>(ei, rowptr, eidx, esrc, edst, a0, N, E);
    aggregate_kernel<<<N, 256, 0, stream>>>(hbuf, a0, ei, rowptr, eidx, b0, xbuf, E);

    // ---- layer 1 (K = 256)
    gemm_kernel<256><<<(N + 15) / 16, 256, 0, stream>>>(xbuf, W1, hbuf, N);
    edge_coef_kernel<<<N, 256, 0, stream>>>(hbuf, as1, ad1, esrc, edst);
    attn_kernel<<<attn_grid, 256, 0, stream>>>(ei, rowptr, eidx, esrc, edst, a1, N, E);
    aggregate_kernel<<<N, 256, 0, stream>>>(hbuf, a1, ei, rowptr, eidx, b1, xbuf, E);

    // ---- layer 2 (K = 256, mean over heads)
    gemm_kernel<256><<<(N + 15) / 16, 256, 0, stream>>>(xbuf, W2, hbuf, N);
    edge_coef_kernel<<<N, 256, 0, stream>>>(hbuf, as2, ad2, esrc, edst);
    attn_kernel<<<attn_grid, 256, 0, stream>>>(ei, rowptr, eidx, esrc, edst, a2, N, E);
    aggregate_mean_kernel<<<N, 256, 0, stream>>>(hbuf, a2, ei, rowptr, eidx, b2, out, E);
}

// Round 2
// 420.748 us; speedup vs baseline: 1.8000x; 1.8000x over previous
//
#include <hip/hip_runtime.h>
#include <hip/hip_bf16.h>
#include <math.h>

#define HCOLS 256          // H * C = 4 * 64, hidden width for all layers
#define NHEAD 4
#define CDIM  64
#define NEG_SLOPE 0.2f

__device__ __forceinline__ float leaky(float v) { return v > 0.f ? v : v * NEG_SLOPE; }
__device__ __forceinline__ float readlane_f(float v, int l) {
    return __uint_as_float(__builtin_amdgcn_readlane(__float_as_uint(v), l));
}

// ---------------------------------------------------------------- CSR build
__global__ void deg_kernel(const int* __restrict__ ei, int* __restrict__ deg,
                           int E, int Ep) {
    int e = blockIdx.x * 256 + threadIdx.x;
    if (e >= Ep) return;
    int d = (e < E) ? ei[E + e] : (e - E);
    atomicAdd(&deg[d], 1);
}

__global__ void scan_kernel(const int* __restrict__ deg, int* __restrict__ rowptr,
                            int* __restrict__ cursor, int n) {
    __shared__ int tmp[1024];
    __shared__ int carry_s;
    int tid = threadIdx.x;
    if (tid == 0) carry_s = 0;
    __syncthreads();
    for (int base = 0; base < n; base += 1024) {
        int i = base + tid;
        int v = (i < n) ? deg[i] : 0;
        tmp[tid] = v;
        __syncthreads();
        for (int off = 1; off < 1024; off <<= 1) {
            int t = (tid >= off) ? tmp[tid - off] : 0;
            __syncthreads();
            tmp[tid] += t;
            __syncthreads();
        }
        int excl = carry_s + tmp[tid] - v;   // read carry before update
        if (i < n) { rowptr[i] = excl; cursor[i] = excl; }
        __syncthreads();
        if (tid == 1023) carry_s += tmp[1023];
        __syncthreads();
    }
    if (tid == 0) rowptr[n] = carry_s;
}

__global__ void fill_kernel(const int* __restrict__ ei, int* __restrict__ cursor,
                            int* __restrict__ eidx, int E, int Ep) {
    int e = blockIdx.x * 256 + threadIdx.x;
    if (e >= Ep) return;
    int d = (e < E) ? ei[E + e] : (e - E);
    int pos = atomicAdd(&cursor[d], 1);
    eidx[pos] = e;
}

// ---------------------------------------------------------------- GEMM  h = X @ W  (+ fused attn coefs)
// block: 256 threads -> 16 rows x 256 cols. X rows staged in LDS.
// wave w == head w (columns head*64..head*64+63), so per-row coef reduction
// is a 64-lane shuffle reduce.
template <int K>
__global__ void gemm_kernel(const float* __restrict__ X, const float* __restrict__ W,
                            float* __restrict__ Hout,
                            const float* __restrict__ As, const float* __restrict__ Ad,
                            float* __restrict__ esrc, float* __restrict__ edst,
                            int n) {
    __shared__ __align__(16) float xs[16][K];
    int row0 = blockIdx.x * 16;
    int tid = threadIdx.x;
    for (int idx = tid; idx < 16 * K; idx += 256) {
        int r = idx / K, k = idx % K;
        int row = row0 + r;
        xs[r][k] = (row < n) ? X[(size_t)row * K + k] : 0.f;
    }
    __syncthreads();
    float acc[16];
#pragma unroll
    for (int r = 0; r < 16; ++r) acc[r] = 0.f;
    for (int k = 0; k < K; k += 4) {
        float w0 = W[(k + 0) * HCOLS + tid];
        float w1 = W[(k + 1) * HCOLS + tid];
        float w2 = W[(k + 2) * HCOLS + tid];
        float w3 = W[(k + 3) * HCOLS + tid];
#pragma unroll
        for (int r = 0; r < 16; ++r) {
            float4 xv = *reinterpret_cast<const float4*>(&xs[r][k]);
            acc[r] = fmaf(xv.x, w0, acc[r]);
            acc[r] = fmaf(xv.y, w1, acc[r]);
            acc[r] = fmaf(xv.z, w2, acc[r]);
            acc[r] = fmaf(xv.w, w3, acc[r]);
        }
    }
#pragma unroll
    for (int r = 0; r < 16; ++r) {
        int row = row0 + r;
        if (row < n) Hout[(size_t)row * HCOLS + tid] = acc[r];
    }
    // fused e_src/e_dst: per row, reduce acc*a over the 64 lanes of this head's wave
    float av = As[tid], dv = Ad[tid];
    int lane = tid & 63;
    int head = tid >> 6;
#pragma unroll
    for (int r = 0; r < 16; ++r) {
        float ps = acc[r] * av;
        float pd = acc[r] * dv;
#pragma unroll
        for (int off = 32; off; off >>= 1) {
            ps += __shfl_xor(ps, off, 64);
            pd += __shfl_xor(pd, off, 64);
        }
        if (lane == 0) {
            int row = row0 + r;
            if (row < n) {
                esrc[row * NHEAD + head] = ps;
                edst[row * NHEAD + head] = pd;
            }
        }
    }
}

// ---------------------------------------------------------------- fused segment-softmax + aggregation
// block = 4 nodes, wave = 1 node.
// Phase A (lane = edge ordinal): one float4 gather of esrc per edge gives all
// 4 heads; shuffle-reduce max/denom; write alpha.
// Phase B (lane = channel quad): per edge, src index + alpha broadcast via
// readlane (scalar base address), wave gathers the 1KB h[src] row as float4.
template <int MODE>  // 0: concat + bias + ELU (out width 256), 1: head-mean + bias (out width 64)
__global__ void attn_agg_kernel(const float* __restrict__ h,
                                const float* __restrict__ esrc,
                                const float* __restrict__ edst,
                                const int* __restrict__ ei,
                                const int* __restrict__ rowptr,
                                const int* __restrict__ eidx,
                                const float* __restrict__ bias,
                                float* __restrict__ alpha,
                                float* __restrict__ xout,
                                int n, int E) {
    int wave = threadIdx.x >> 6;
    int lane = threadIdx.x & 63;
    int node = blockIdx.x * 4 + wave;
    if (node >= n) return;
    int s0 = rowptr[node], s1 = rowptr[node + 1];
    int deg = s1 - s0;
    float4 ed = *reinterpret_cast<const float4*>(&edst[node * NHEAD]);

    // ---------- phase A: softmax
    int i0 = s0 + lane;
    bool valid = i0 < s1;
    int e0 = 0, sv = 0;
    float4 lg0 = make_float4(-3.4e38f, -3.4e38f, -3.4e38f, -3.4e38f);
    if (valid) {
        e0 = eidx[i0];
        sv = (e0 < E) ? ei[e0] : (e0 - E);
        float4 es = *reinterpret_cast<const float4*>(&esrc[sv * NHEAD]);
        lg0.x = leaky(es.x + ed.x);
        lg0.y = leaky(es.y + ed.y);
        lg0.z = leaky(es.z + ed.z);
        lg0.w = leaky(es.w + ed.w);
    }
    float4 mx = lg0;
    for (int i = i0 + 64; i < s1; i += 64) {          // rare: deg > 64
        int e = eidx[i];
        int s = (e < E) ? ei[e] : (e - E);
        float4 es = *reinterpret_cast<const float4*>(&esrc[s * NHEAD]);
        mx.x = fmaxf(mx.x, leaky(es.x + ed.x));
        mx.y = fmaxf(mx.y, leaky(es.y + ed.y));
        mx.z = fmaxf(mx.z, leaky(es.z + ed.z));
        mx.w = fmaxf(mx.w, leaky(es.w + ed.w));
    }
#pragma unroll
    for (int off = 32; off; off >>= 1) {
        mx.x = fmaxf(mx.x, __shfl_xor(mx.x, off, 64));
        mx.y = fmaxf(mx.y, __shfl_xor(mx.y, off, 64));
        mx.z = fmaxf(mx.z, __shfl_xor(mx.z, off, 64));
        mx.w = fmaxf(mx.w, __shfl_xor(mx.w, off, 64));
    }
    float4 ex0 = make_float4(0.f, 0.f, 0.f, 0.f);
    if (valid) {
        ex0.x = __expf(lg0.x - mx.x);
        ex0.y = __expf(lg0.y - mx.y);
        ex0.z = __expf(lg0.z - mx.z);
        ex0.w = __expf(lg0.w - mx.w);
    }
    float4 sm = ex0;
    for (int i = i0 + 64; i < s1; i += 64) {          // rare
        int e = eidx[i];
        int s = (e < E) ? ei[e] : (e - E);
        float4 es = *reinterpret_cast<const float4*>(&esrc[s * NHEAD]);
        sm.x += __expf(leaky(es.x + ed.x) - mx.x);
        sm.y += __expf(leaky(es.y + ed.y) - mx.y);
        sm.z += __expf(leaky(es.z + ed.z) - mx.z);
        sm.w += __expf(leaky(es.w + ed.w) - mx.w);
    }
#pragma unroll
    for (int off = 32; off; off >>= 1) {
        sm.x += __shfl_xor(sm.x, off, 64);
        sm.y += __shfl_xor(sm.y, off, 64);
        sm.z += __shfl_xor(sm.z, off, 64);
        sm.w += __shfl_xor(sm.w, off, 64);
    }
    float4 inv = make_float4(1.f / sm.x, 1.f / sm.y, 1.f / sm.z, 1.f / sm.w);
    float4 al = make_float4(ex0.x * inv.x, ex0.y * inv.y, ex0.z * inv.z, ex0.w * inv.w);
    if (valid) *reinterpret_cast<float4*>(&alpha[(size_t)e0 * NHEAD]) = al;
    for (int i = i0 + 64; i < s1; i += 64) {          // rare
        int e = eidx[i];
        int s = (e < E) ? ei[e] : (e - E);
        float4 es = *reinterpret_cast<const float4*>(&esrc[s * NHEAD]);
        float4 av;
        av.x = __expf(leaky(es.x + ed.x) - mx.x) * inv.x;
        av.y = __expf(leaky(es.y + ed.y) - mx.y) * inv.y;
        av.z = __expf(leaky(es.z + ed.z) - mx.z) * inv.z;
        av.w = __expf(leaky(es.w + ed.w) - mx.w) * inv.w;
        *reinterpret_cast<float4*>(&alpha[(size_t)e * NHEAD]) = av;
    }
    bool big = deg > 64;
    if (big) __threadfence();   // make slow-path alpha visible for phase B reads

    // ---------- phase B: aggregate out[node] = sum_e alpha[e] * h[src(e)]
    int head = lane >> 4;                 // lane covers channels lane*4..lane*4+3
    float4 acc = make_float4(0.f, 0.f, 0.f, 0.f);
    int m = deg < 64 ? deg : 64;
    for (int j = 0; j < m; ++j) {
        int s = __builtin_amdgcn_readlane(sv, j);
        float a0v = readlane_f(al.x, j);
        float a1v = readlane_f(al.y, j);
        float a2v = readlane_f(al.z, j);
        float a3v = readlane_f(al.w, j);
        float a = (head & 2) ? ((head & 1) ? a3v : a2v) : ((head & 1) ? a1v : a0v);
        float4 hv = *reinterpret_cast<const float4*>(&h[(size_t)s * HCOLS + (lane << 2)]);
        acc.x = fmaf(a, hv.x, acc.x);
        acc.y = fmaf(a, hv.y, acc.y);
        acc.z = fmaf(a, hv.z, acc.z);
        acc.w = fmaf(a, hv.w, acc.w);
    }
    if (big) {                            // rare slow path
        for (int i = s0 + 64; i < s1; ++i) {
            int e = eidx[i];
            int s = (e < E) ? ei[e] : (e - E);
            float4 av = *reinterpret_cast<const float4*>(&alpha[(size_t)e * NHEAD]);
            float a = (head & 2) ? ((head & 1) ? av.w : av.z) : ((head & 1) ? av.y : av.x);
            float4 hv = *reinterpret_cast<const float4*>(&h[(size_t)s * HCOLS + (lane << 2)]);
            acc.x = fmaf(a, hv.x, acc.x);
            acc.y = fmaf(a, hv.y, acc.y);
            acc.z = fmaf(a, hv.z, acc.z);
            acc.w = fmaf(a, hv.w, acc.w);
        }
    }
    if (MODE == 0) {
        float4 bv = *reinterpret_cast<const float4*>(&bias[lane << 2]);
        float4 v;
        v.x = acc.x + bv.x; v.y = acc.y + bv.y; v.z = acc.z + bv.z; v.w = acc.w + bv.w;
        v.x = v.x > 0.f ? v.x : expm1f(v.x);
        v.y = v.y > 0.f ? v.y : expm1f(v.y);
        v.z = v.z > 0.f ? v.z : expm1f(v.z);
        v.w = v.w > 0.f ? v.w : expm1f(v.w);
        *reinterpret_cast<float4*>(&xout[(size_t)node * HCOLS + (lane << 2)]) = v;
    } else {
        // mean over heads: sum the 4 head groups (lanes xor 16, xor 32)
        acc.x += __shfl_xor(acc.x, 16, 64); acc.x += __shfl_xor(acc.x, 32, 64);
        acc.y += __shfl_xor(acc.y, 16, 64); acc.y += __shfl_xor(acc.y, 32, 64);
        acc.z += __shfl_xor(acc.z, 16, 64); acc.z += __shfl_xor(acc.z, 32, 64);
        acc.w += __shfl_xor(acc.w, 16, 64); acc.w += __shfl_xor(acc.w, 32, 64);
        if (lane < 16) {
            float4 bv = *reinterpret_cast<const float4*>(&bias[lane << 2]);
            float4 v;
            v.x = acc.x * 0.25f + bv.x;
            v.y = acc.y * 0.25f + bv.y;
            v.z = acc.z * 0.25f + bv.z;
            v.w = acc.w * 0.25f + bv.w;
            *reinterpret_cast<float4*>(&xout[(size_t)node * CDIM + (lane << 2)]) = v;
        }
    }
}

// ---------------------------------------------------------------- launch
extern "C" void kernel_launch(void* const* d_in, const int* in_sizes, int n_in,
                              void* d_out, int out_size, void* d_ws, size_t ws_size,
                              hipStream_t stream) {
    const float* x   = (const float*)d_in[0];
    const int*   ei  = (const int*)d_in[1];
    const float* W0  = (const float*)d_in[2];
    const float* as0 = (const float*)d_in[3];
    const float* ad0 = (const float*)d_in[4];
    const float* b0  = (const float*)d_in[5];
    const float* W1  = (const float*)d_in[6];
    const float* as1 = (const float*)d_in[7];
    const float* ad1 = (const float*)d_in[8];
    const float* b1  = (const float*)d_in[9];
    const float* W2  = (const float*)d_in[10];
    const float* as2 = (const float*)d_in[11];
    const float* ad2 = (const float*)d_in[12];
    const float* b2  = (const float*)d_in[13];

    const int N  = in_sizes[0] / 128;
    const int E  = in_sizes[1] / 2;
    const int Ep = E + N;

    float* out = (float*)d_out;
    float* a0  = out + (size_t)N * CDIM;
    float* a1  = a0 + (size_t)Ep * NHEAD;
    float* a2  = a1 + (size_t)Ep * NHEAD;

    char* wp = (char*)d_ws;
    auto carve = [&](size_t bytes) {
        char* p = wp;
        wp += (bytes + 255) & ~(size_t)255;
        return (void*)p;
    };
    float* hbuf   = (float*)carve((size_t)N * HCOLS * 4);
    float* xbuf   = (float*)carve((size_t)N * HCOLS * 4);
    float* esrc   = (float*)carve((size_t)N * NHEAD * 4);
    float* edst   = (float*)carve((size_t)N * NHEAD * 4);
    int*   deg    = (int*)carve((size_t)N * 4);
    int*   rowptr = (int*)carve((size_t)(N + 1) * 4);
    int*   cursor = (int*)carve((size_t)N * 4);
    int*   eidx   = (int*)carve((size_t)Ep * 4);

    // CSR by dst (graph identical for all layers)
    hipMemsetAsync(deg, 0, (size_t)N * 4, stream);
    deg_kernel<<<(Ep + 255) / 256, 256, 0, stream>>>(ei, deg, E, Ep);
    scan_kernel<<<1, 1024, 0, stream>>>(deg, rowptr, cursor, N);
    fill_kernel<<<(Ep + 255) / 256, 256, 0, stream>>>(ei, cursor, eidx, E, Ep);

    int agg_grid = (N + 3) / 4;

    // ---- layer 0 (K = 128)
    gemm_kernel<128><<<(N + 15) / 16, 256, 0, stream>>>(x, W0, hbuf, as0, ad0, esrc, edst, N);
    attn_agg_kernel<0><<<agg_grid, 256, 0, stream>>>(hbuf, esrc, edst, ei, rowptr, eidx, b0, a0, xbuf, N, E);

    // ---- layer 1 (K = 256)
    gemm_kernel<256><<<(N + 15) / 16, 256, 0, stream>>>(xbuf, W1, hbuf, as1, ad1, esrc, edst, N);
    attn_agg_kernel<0><<<agg_grid, 256, 0, stream>>>(hbuf, esrc, edst, ei, rowptr, eidx, b1, a1, xbuf, N, E);

    // ---- layer 2 (K = 256, mean over heads)
    gemm_kernel<256><<<(N + 15) / 16, 256, 0, stream>>>(xbuf, W2, hbuf, as2, ad2, esrc, edst, N);
    attn_agg_kernel<1><<<agg_grid, 256, 0, stream>>>(hbuf, esrc, edst, ei, rowptr, eidx, b2, a2, out, N, E);
}

// Round 3
// 270.824 us; speedup vs baseline: 2.7965x; 1.5536x over previous
//
#include <hip/hip_runtime.h>
#include <hip/hip_bf16.h>
#include <math.h>

#define HCOLS 256          // H * C = 4 * 64, hidden width for all layers
#define NHEAD 4
#define CDIM  64
#define NEG_SLOPE 0.2f

typedef __attribute__((ext_vector_type(8))) short bf16x8;
typedef __attribute__((ext_vector_type(4))) float f32x4;

__device__ __forceinline__ float leaky(float v) { return v > 0.f ? v : v * NEG_SLOPE; }
__device__ __forceinline__ float readlane_f(float v, int l) {
    return __uint_as_float(__builtin_amdgcn_readlane(__float_as_uint(v), l));
}
__device__ __forceinline__ unsigned short f2bf(float f) {      // RNE
    unsigned u = __float_as_uint(f);
    u += 0x7fff + ((u >> 16) & 1);
    return (unsigned short)(u >> 16);
}
__device__ __forceinline__ float bf2f(unsigned short b) {
    return __uint_as_float(((unsigned)b) << 16);
}

// ---------------------------------------------------------------- CSR build
__global__ void deg_kernel(const int* __restrict__ ei, int* __restrict__ deg,
                           int E, int Ep) {
    int e = blockIdx.x * 256 + threadIdx.x;
    if (e >= Ep) return;
    int d = (e < E) ? ei[E + e] : (e - E);
    atomicAdd(&deg[d], 1);
}

__global__ void scan_kernel(const int* __restrict__ deg, int* __restrict__ rowptr,
                            int* __restrict__ cursor, int n) {
    __shared__ int tmp[1024];
    __shared__ int carry_s;
    int tid = threadIdx.x;
    if (tid == 0) carry_s = 0;
    __syncthreads();
    for (int base = 0; base < n; base += 1024) {
        int i = base + tid;
        int v = (i < n) ? deg[i] : 0;
        tmp[tid] = v;
        __syncthreads();
        for (int off = 1; off < 1024; off <<= 1) {
            int t = (tid >= off) ? tmp[tid - off] : 0;
            __syncthreads();
            tmp[tid] += t;
            __syncthreads();
        }
        int excl = carry_s + tmp[tid] - v;
        if (i < n) { rowptr[i] = excl; cursor[i] = excl; }
        __syncthreads();
        if (tid == 1023) carry_s += tmp[1023];
        __syncthreads();
    }
    if (tid == 0) rowptr[n] = carry_s;
}

__global__ void fill_kernel(const int* __restrict__ ei, int* __restrict__ cursor,
                            int* __restrict__ eidx, int E, int Ep) {
    int e = blockIdx.x * 256 + threadIdx.x;
    if (e >= Ep) return;
    int d = (e < E) ? ei[E + e] : (e - E);
    int pos = atomicAdd(&cursor[d], 1);
    eidx[pos] = e;
}

// ---------------------------------------------------------------- W transpose+convert:  Wt[col][k] = bf16(W[k][col])
__global__ void wconv_kernel(const float* __restrict__ W, unsigned short* __restrict__ Wt, int K) {
    __shared__ float t[32][33];
    int bx = blockIdx.x;                 // col tile (over 256)
    int by = blockIdx.y;                 // k tile (over K)
    int tx = threadIdx.x & 31, ty = threadIdx.x >> 5;   // 32 x 8
#pragma unroll
    for (int i = 0; i < 32; i += 8)
        t[ty + i][tx] = W[(by * 32 + ty + i) * HCOLS + bx * 32 + tx];
    __syncthreads();
#pragma unroll
    for (int i = 0; i < 32; i += 8)
        Wt[(size_t)(bx * 32 + ty + i) * K + by * 32 + tx] = f2bf(t[tx][ty + i]);
}

// ---------------------------------------------------------------- MFMA GEMM  h = X @ W (+ fused attn coefs)
// block: 256 thr = 4 waves; 32 rows x 256 cols. wave w -> cols [64w,64w+64) == head w.
// A (bf16) staged in LDS padded; B from Wt[col][k] (bf16, L2-resident).
// mfma_f32_16x16x32_bf16:  A: row=l&15, k=(l>>4)*8+i ; B: col=l&15, k=(l>>4)*8+i ;
// C/D: col=l&15, row=(l>>4)*4+j   [m89-verified]
template <int K, bool SRC_F32>
__global__ void gemm_kernel(const void* __restrict__ Xv, const unsigned short* __restrict__ Wt,
                            unsigned short* __restrict__ Hout,
                            const float* __restrict__ As, const float* __restrict__ Ad,
                            float* __restrict__ esrc, float* __restrict__ edst,
                            int n) {
    constexpr int LDK = K + 16;                     // pad: stride 2*(K+16) bytes -> conflict-free ds_read_b128
    __shared__ __align__(16) unsigned short a_sh[32 * LDK];
    int row0 = blockIdx.x * 32;
    int tid = threadIdx.x;

    // ---- stage A tile (32 x K) as bf16
    constexpr int CH = 32 * K / 8;                  // 16B chunks
    for (int c = tid; c < CH; c += 256) {
        int r = c / (K / 8), kc = c % (K / 8);
        int row = row0 + r;
        uint4 pack;
        if (row < n) {
            if (SRC_F32) {
                const float* X = (const float*)Xv;
                float4 f0 = *reinterpret_cast<const float4*>(&X[(size_t)row * K + kc * 8]);
                float4 f1 = *reinterpret_cast<const float4*>(&X[(size_t)row * K + kc * 8 + 4]);
                pack.x = f2bf(f0.x) | ((unsigned)f2bf(f0.y) << 16);
                pack.y = f2bf(f0.z) | ((unsigned)f2bf(f0.w) << 16);
                pack.z = f2bf(f1.x) | ((unsigned)f2bf(f1.y) << 16);
                pack.w = f2bf(f1.z) | ((unsigned)f2bf(f1.w) << 16);
            } else {
                const uint4* X = (const uint4*)Xv;
                pack = X[((size_t)row * K + kc * 8) / 8];
            }
        } else {
            pack = make_uint4(0, 0, 0, 0);
        }
        *reinterpret_cast<uint4*>(&a_sh[r * LDK + kc * 8]) = pack;
    }
    __syncthreads();

    int lane = tid & 63;
    int w = tid >> 6;                              // wave == head
    int lr = lane & 15;                            // row / col within fragment
    int lk = (lane >> 4) * 8;                      // k offset within fragment

    f32x4 acc[2][4];
#pragma unroll
    for (int m = 0; m < 2; ++m)
#pragma unroll
        for (int nf = 0; nf < 4; ++nf) acc[m][nf] = (f32x4){0.f, 0.f, 0.f, 0.f};

    const unsigned short* wt = Wt + (size_t)(w * 64) * K;
#pragma unroll
    for (int ks = 0; ks < K / 32; ++ks) {
        bf16x8 a[2], b[4];
#pragma unroll
        for (int m = 0; m < 2; ++m)
            a[m] = *reinterpret_cast<const bf16x8*>(&a_sh[(16 * m + lr) * LDK + ks * 32 + lk]);
#pragma unroll
        for (int nf = 0; nf < 4; ++nf)
            b[nf] = *reinterpret_cast<const bf16x8*>(&wt[(size_t)(16 * nf + lr) * K + ks * 32 + lk]);
#pragma unroll
        for (int m = 0; m < 2; ++m)
#pragma unroll
            for (int nf = 0; nf < 4; ++nf)
                acc[m][nf] = __builtin_amdgcn_mfma_f32_16x16x32_bf16(a[m], b[nf], acc[m][nf], 0, 0, 0);
    }

    // ---- store h (bf16) + fused esrc/edst (per-head reduce within wave)
    float as_v[4], ad_v[4];
#pragma unroll
    for (int nf = 0; nf < 4; ++nf) {
        as_v[nf] = As[w * 64 + 16 * nf + lr];
        ad_v[nf] = Ad[w * 64 + 16 * nf + lr];
    }
#pragma unroll
    for (int m = 0; m < 2; ++m) {
#pragma unroll
        for (int j = 0; j < 4; ++j) {
            int row_g = row0 + 16 * m + (lane >> 4) * 4 + j;
            bool ok = row_g < n;
#pragma unroll
            for (int nf = 0; nf < 4; ++nf) {
                if (ok) Hout[(size_t)row_g * HCOLS + w * 64 + 16 * nf + lr] = f2bf(acc[m][nf][j]);
            }
            float ps = acc[m][0][j] * as_v[0] + acc[m][1][j] * as_v[1] +
                       acc[m][2][j] * as_v[2] + acc[m][3][j] * as_v[3];
            float pd = acc[m][0][j] * ad_v[0] + acc[m][1][j] * ad_v[1] +
                       acc[m][2][j] * ad_v[2] + acc[m][3][j] * ad_v[3];
#pragma unroll
            for (int off = 1; off < 16; off <<= 1) {
                ps += __shfl_xor(ps, off, 64);
                pd += __shfl_xor(pd, off, 64);
            }
            if (lr == 0 && ok) {
                esrc[row_g * NHEAD + w] = ps;
                edst[row_g * NHEAD + w] = pd;
            }
        }
    }
}

// ---------------------------------------------------------------- fused segment-softmax + aggregation
// block = 4 nodes, wave = 1 node. h is bf16 (512B/row gather).
template <int MODE>  // 0: concat+bias+ELU -> bf16 xout (width 256), 1: head-mean+bias -> f32 out (width 64)
__global__ void attn_agg_kernel(const unsigned short* __restrict__ h,
                                const float* __restrict__ esrc,
                                const float* __restrict__ edst,
                                const int* __restrict__ ei,
                                const int* __restrict__ rowptr,
                                const int* __restrict__ eidx,
                                const float* __restrict__ bias,
                                float* __restrict__ alpha,
                                void* __restrict__ xout,
                                int n, int E) {
    int wave = threadIdx.x >> 6;
    int lane = threadIdx.x & 63;
    int node = blockIdx.x * 4 + wave;
    if (node >= n) return;
    int s0 = rowptr[node], s1 = rowptr[node + 1];
    int deg = s1 - s0;
    float4 ed = *reinterpret_cast<const float4*>(&edst[node * NHEAD]);

    // ---------- phase A: segment softmax
    int i0 = s0 + lane;
    bool valid = i0 < s1;
    int e0 = 0, sv = 0;
    float4 lg0 = make_float4(-3.4e38f, -3.4e38f, -3.4e38f, -3.4e38f);
    if (valid) {
        e0 = eidx[i0];
        sv = (e0 < E) ? ei[e0] : (e0 - E);
        float4 es = *reinterpret_cast<const float4*>(&esrc[sv * NHEAD]);
        lg0.x = leaky(es.x + ed.x);
        lg0.y = leaky(es.y + ed.y);
        lg0.z = leaky(es.z + ed.z);
        lg0.w = leaky(es.w + ed.w);
    }
    float4 mx = lg0;
    for (int i = i0 + 64; i < s1; i += 64) {          // rare: deg > 64
        int e = eidx[i];
        int s = (e < E) ? ei[e] : (e - E);
        float4 es = *reinterpret_cast<const float4*>(&esrc[s * NHEAD]);
        mx.x = fmaxf(mx.x, leaky(es.x + ed.x));
        mx.y = fmaxf(mx.y, leaky(es.y + ed.y));
        mx.z = fmaxf(mx.z, leaky(es.z + ed.z));
        mx.w = fmaxf(mx.w, leaky(es.w + ed.w));
    }
#pragma unroll
    for (int off = 32; off; off >>= 1) {
        mx.x = fmaxf(mx.x, __shfl_xor(mx.x, off, 64));
        mx.y = fmaxf(mx.y, __shfl_xor(mx.y, off, 64));
        mx.z = fmaxf(mx.z, __shfl_xor(mx.z, off, 64));
        mx.w = fmaxf(mx.w, __shfl_xor(mx.w, off, 64));
    }
    float4 ex0 = make_float4(0.f, 0.f, 0.f, 0.f);
    if (valid) {
        ex0.x = __expf(lg0.x - mx.x);
        ex0.y = __expf(lg0.y - mx.y);
        ex0.z = __expf(lg0.z - mx.z);
        ex0.w = __expf(lg0.w - mx.w);
    }
    float4 sm = ex0;
    for (int i = i0 + 64; i < s1; i += 64) {          // rare
        int e = eidx[i];
        int s = (e < E) ? ei[e] : (e - E);
        float4 es = *reinterpret_cast<const float4*>(&esrc[s * NHEAD]);
        sm.x += __expf(leaky(es.x + ed.x) - mx.x);
        sm.y += __expf(leaky(es.y + ed.y) - mx.y);
        sm.z += __expf(leaky(es.z + ed.z) - mx.z);
        sm.w += __expf(leaky(es.w + ed.w) - mx.w);
    }
#pragma unroll
    for (int off = 32; off; off >>= 1) {
        sm.x += __shfl_xor(sm.x, off, 64);
        sm.y += __shfl_xor(sm.y, off, 64);
        sm.z += __shfl_xor(sm.z, off, 64);
        sm.w += __shfl_xor(sm.w, off, 64);
    }
    float4 inv = make_float4(1.f / sm.x, 1.f / sm.y, 1.f / sm.z, 1.f / sm.w);
    float4 al = make_float4(ex0.x * inv.x, ex0.y * inv.y, ex0.z * inv.z, ex0.w * inv.w);
    if (valid) *reinterpret_cast<float4*>(&alpha[(size_t)e0 * NHEAD]) = al;
    for (int i = i0 + 64; i < s1; i += 64) {          // rare
        int e = eidx[i];
        int s = (e < E) ? ei[e] : (e - E);
        float4 es = *reinterpret_cast<const float4*>(&esrc[s * NHEAD]);
        float4 av;
        av.x = __expf(leaky(es.x + ed.x) - mx.x) * inv.x;
        av.y = __expf(leaky(es.y + ed.y) - mx.y) * inv.y;
        av.z = __expf(leaky(es.z + ed.z) - mx.z) * inv.z;
        av.w = __expf(leaky(es.w + ed.w) - mx.w) * inv.w;
        *reinterpret_cast<float4*>(&alpha[(size_t)e * NHEAD]) = av;
    }
    bool big = deg > 64;
    if (big) __threadfence();

    // ---------- phase B: out[node] = sum_e alpha[e] * h[src(e)]   (h bf16, 512B/row)
    int head = lane >> 4;                 // lane covers channels lane*4..lane*4+3
    float4 acc = make_float4(0.f, 0.f, 0.f, 0.f);
    int m = deg < 64 ? deg : 64;
    for (int j = 0; j < m; ++j) {
        int s = __builtin_amdgcn_readlane(sv, j);
        float a0v = readlane_f(al.x, j);
        float a1v = readlane_f(al.y, j);
        float a2v = readlane_f(al.z, j);
        float a3v = readlane_f(al.w, j);
        float a = (head & 2) ? ((head & 1) ? a3v : a2v) : ((head & 1) ? a1v : a0v);
        ushort4 hv = *reinterpret_cast<const ushort4*>(&h[(size_t)s * HCOLS + (lane << 2)]);
        acc.x = fmaf(a, bf2f(hv.x), acc.x);
        acc.y = fmaf(a, bf2f(hv.y), acc.y);
        acc.z = fmaf(a, bf2f(hv.z), acc.z);
        acc.w = fmaf(a, bf2f(hv.w), acc.w);
    }
    if (big) {                            // rare slow path
        for (int i = s0 + 64; i < s1; ++i) {
            int e = eidx[i];
            int s = (e < E) ? ei[e] : (e - E);
            float4 av = *reinterpret_cast<const float4*>(&alpha[(size_t)e * NHEAD]);
            float a = (head & 2) ? ((head & 1) ? av.w : av.z) : ((head & 1) ? av.y : av.x);
            ushort4 hv = *reinterpret_cast<const ushort4*>(&h[(size_t)s * HCOLS + (lane << 2)]);
            acc.x = fmaf(a, bf2f(hv.x), acc.x);
            acc.y = fmaf(a, bf2f(hv.y), acc.y);
            acc.z = fmaf(a, bf2f(hv.z), acc.z);
            acc.w = fmaf(a, bf2f(hv.w), acc.w);
        }
    }
    if (MODE == 0) {
        float4 bv = *reinterpret_cast<const float4*>(&bias[lane << 2]);
        float4 v;
        v.x = acc.x + bv.x; v.y = acc.y + bv.y; v.z = acc.z + bv.z; v.w = acc.w + bv.w;
        v.x = v.x > 0.f ? v.x : expm1f(v.x);
        v.y = v.y > 0.f ? v.y : expm1f(v.y);
        v.z = v.z > 0.f ? v.z : expm1f(v.z);
        v.w = v.w > 0.f ? v.w : expm1f(v.w);
        ushort4 o;
        o.x = f2bf(v.x); o.y = f2bf(v.y); o.z = f2bf(v.z); o.w = f2bf(v.w);
        *reinterpret_cast<ushort4*>(&((unsigned short*)xout)[(size_t)node * HCOLS + (lane << 2)]) = o;
    } else {
        acc.x += __shfl_xor(acc.x, 16, 64); acc.x += __shfl_xor(acc.x, 32, 64);
        acc.y += __shfl_xor(acc.y, 16, 64); acc.y += __shfl_xor(acc.y, 32, 64);
        acc.z += __shfl_xor(acc.z, 16, 64); acc.z += __shfl_xor(acc.z, 32, 64);
        acc.w += __shfl_xor(acc.w, 16, 64); acc.w += __shfl_xor(acc.w, 32, 64);
        if (lane < 16) {
            float4 bv = *reinterpret_cast<const float4*>(&bias[lane << 2]);
            float4 v;
            v.x = acc.x * 0.25f + bv.x;
            v.y = acc.y * 0.25f + bv.y;
            v.z = acc.z * 0.25f + bv.z;
            v.w = acc.w * 0.25f + bv.w;
            *reinterpret_cast<float4*>(&((float*)xout)[(size_t)node * CDIM + (lane << 2)]) = v;
        }
    }
}

// ---------------------------------------------------------------- launch
extern "C" void kernel_launch(void* const* d_in, const int* in_sizes, int n_in,
                              void* d_out, int out_size, void* d_ws, size_t ws_size,
                              hipStream_t stream) {
    const float* x   = (const float*)d_in[0];
    const int*   ei  = (const int*)d_in[1];
    const float* W0  = (const float*)d_in[2];
    const float* as0 = (const float*)d_in[3];
    const float* ad0 = (const float*)d_in[4];
    const float* b0  = (const float*)d_in[5];
    const float* W1  = (const float*)d_in[6];
    const float* as1 = (const float*)d_in[7];
    const float* ad1 = (const float*)d_in[8];
    const float* b1  = (const float*)d_in[9];
    const float* W2  = (const float*)d_in[10];
    const float* as2 = (const float*)d_in[11];
    const float* ad2 = (const float*)d_in[12];
    const float* b2  = (const float*)d_in[13];

    const int N  = in_sizes[0] / 128;
    const int E  = in_sizes[1] / 2;
    const int Ep = E + N;

    float* out = (float*)d_out;
    float* a0  = out + (size_t)N * CDIM;
    float* a1  = a0 + (size_t)Ep * NHEAD;
    float* a2  = a1 + (size_t)Ep * NHEAD;

    char* wp = (char*)d_ws;
    auto carve = [&](size_t bytes) {
        char* p = wp;
        wp += (bytes + 255) & ~(size_t)255;
        return (void*)p;
    };
    unsigned short* hbuf = (unsigned short*)carve((size_t)N * HCOLS * 2);   // bf16
    unsigned short* xbuf = (unsigned short*)carve((size_t)N * HCOLS * 2);   // bf16
    float* esrc   = (float*)carve((size_t)N * NHEAD * 4);
    float* edst   = (float*)carve((size_t)N * NHEAD * 4);
    int*   deg    = (int*)carve((size_t)N * 4);
    int*   rowptr = (int*)carve((size_t)(N + 1) * 4);
    int*   cursor = (int*)carve((size_t)N * 4);
    int*   eidx   = (int*)carve((size_t)Ep * 4);
    unsigned short* Wt0 = (unsigned short*)carve((size_t)HCOLS * 128 * 2);
    unsigned short* Wt1 = (unsigned short*)carve((size_t)HCOLS * HCOLS * 2);
    unsigned short* Wt2 = (unsigned short*)carve((size_t)HCOLS * HCOLS * 2);

    // CSR by dst (graph identical for all layers)
    hipMemsetAsync(deg, 0, (size_t)N * 4, stream);
    deg_kernel<<<(Ep + 255) / 256, 256, 0, stream>>>(ei, deg, E, Ep);
    scan_kernel<<<1, 1024, 0, stream>>>(deg, rowptr, cursor, N);
    fill_kernel<<<(Ep + 255) / 256, 256, 0, stream>>>(ei, cursor, eidx, E, Ep);

    // W -> bf16 transposed
    wconv_kernel<<<dim3(8, 4), 256, 0, stream>>>(W0, Wt0, 128);
    wconv_kernel<<<dim3(8, 8), 256, 0, stream>>>(W1, Wt1, 256);
    wconv_kernel<<<dim3(8, 8), 256, 0, stream>>>(W2, Wt2, 256);

    int gemm_grid = (N + 31) / 32;
    int agg_grid  = (N + 3) / 4;

    // ---- layer 0 (K = 128, fp32 source)
    gemm_kernel<128, true><<<gemm_grid, 256, 0, stream>>>(x, Wt0, hbuf, as0, ad0, esrc, edst, N);
    attn_agg_kernel<0><<<agg_grid, 256, 0, stream>>>(hbuf, esrc, edst, ei, rowptr, eidx, b0, a0, xbuf, N, E);

    // ---- layer 1 (K = 256, bf16 source)
    gemm_kernel<256, false><<<gemm_grid, 256, 0, stream>>>(xbuf, Wt1, hbuf, as1, ad1, esrc, edst, N);
    attn_agg_kernel<0><<<agg_grid, 256, 0, stream>>>(hbuf, esrc, edst, ei, rowptr, eidx, b1, a1, xbuf, N, E);

    // ---- layer 2 (K = 256, bf16 source, mean over heads)
    gemm_kernel<256, false><<<gemm_grid, 256, 0, stream>>>(xbuf, Wt2, hbuf, as2, ad2, esrc, edst, N);
    attn_agg_kernel<1><<<agg_grid, 256, 0, stream>>>(hbuf, esrc, edst, ei, rowptr, eidx, b2, a2, out, N, E);
}

// Round 4
// 244.124 us; speedup vs baseline: 3.1024x; 1.1094x over previous
//
#include <hip/hip_runtime.h>
#include <hip/hip_bf16.h>
#include <math.h>

#define HCOLS 256          // H * C = 4 * 64, hidden width for all layers
#define NHEAD 4
#define CDIM  64
#define NEG_SLOPE 0.2f

typedef __attribute__((ext_vector_type(8))) short bf16x8;
typedef __attribute__((ext_vector_type(4))) float f32x4;

__device__ __forceinline__ float leaky(float v) { return v > 0.f ? v : v * NEG_SLOPE; }
__device__ __forceinline__ unsigned short f2bf(float f) {      // RNE
    unsigned u = __float_as_uint(f);
    u += 0x7fff + ((u >> 16) & 1);
    return (unsigned short)(u >> 16);
}
__device__ __forceinline__ float bf2f(unsigned short b) {
    return __uint_as_float(((unsigned)b) << 16);
}

// ---------------------------------------------------------------- CSR build
__global__ void deg_kernel(const int* __restrict__ ei, int* __restrict__ deg,
                           int E, int Ep) {
    int e = blockIdx.x * 256 + threadIdx.x;
    if (e >= Ep) return;
    int d = (e < E) ? ei[E + e] : (e - E);
    atomicAdd(&deg[d], 1);
}

// 1024 threads, thread owns CH contiguous elems: local sum -> shuffle scan -> local write-back
__global__ void scan_kernel(const int* __restrict__ deg, int* __restrict__ rowptr,
                            int* __restrict__ cursor, int n) {
    __shared__ int wsum[16];
    int tid = threadIdx.x;
    int lane = tid & 63, w = tid >> 6;
    int CH = (n + 1023) >> 10;
    int base = tid * CH;
    int s = 0;
    for (int k = 0; k < CH; ++k) {
        int i = base + k;
        s += (i < n) ? deg[i] : 0;
    }
    int incl = s;
#pragma unroll
    for (int d = 1; d < 64; d <<= 1) {
        int t = __shfl_up(incl, d, 64);
        if (lane >= d) incl += t;
    }
    if (lane == 63) wsum[w] = incl;
    __syncthreads();
    if (w == 0) {
        int v = (lane < 16) ? wsum[lane] : 0;
#pragma unroll
        for (int d = 1; d < 16; d <<= 1) {
            int t = __shfl_up(v, d, 64);
            if (lane >= d) v += t;
        }
        if (lane < 16) wsum[lane] = v;   // inclusive wave sums
    }
    __syncthreads();
    int woff = (w == 0) ? 0 : wsum[w - 1];
    int run = woff + incl - s;           // exclusive prefix of my chunk
    for (int k = 0; k < CH; ++k) {
        int i = base + k;
        if (i < n) { rowptr[i] = run; cursor[i] = run; run += deg[i]; }
    }
    if (tid == 1023) rowptr[n] = run;
}

__global__ void fill_kernel(const int* __restrict__ ei, int* __restrict__ cursor,
                            int* __restrict__ eidx, int E, int Ep) {
    int e = blockIdx.x * 256 + threadIdx.x;
    if (e >= Ep) return;
    int d = (e < E) ? ei[E + e] : (e - E);
    int pos = atomicAdd(&cursor[d], 1);
    eidx[pos] = e;
}

// ---------------------------------------------------------------- W transpose+convert:  Wt[col][k] = bf16(W[k][col])
__global__ void wconv_kernel(const float* __restrict__ W, unsigned short* __restrict__ Wt, int K) {
    __shared__ float t[32][33];
    int bx = blockIdx.x;                 // col tile (over 256)
    int by = blockIdx.y;                 // k tile (over K)
    int tx = threadIdx.x & 31, ty = threadIdx.x >> 5;   // 32 x 8
#pragma unroll
    for (int i = 0; i < 32; i += 8)
        t[ty + i][tx] = W[(by * 32 + ty + i) * HCOLS + bx * 32 + tx];
    __syncthreads();
#pragma unroll
    for (int i = 0; i < 32; i += 8)
        Wt[(size_t)(bx * 32 + ty + i) * K + by * 32 + tx] = f2bf(t[tx][ty + i]);
}

// ---------------------------------------------------------------- MFMA GEMM  h = X @ W (+ fused attn coefs)
// block: 256 thr = 4 waves; 32 rows x 256 cols. wave w -> cols [64w,64w+64) == head w.
template <int K, bool SRC_F32>
__global__ void gemm_kernel(const void* __restrict__ Xv, const unsigned short* __restrict__ Wt,
                            unsigned short* __restrict__ Hout,
                            const float* __restrict__ As, const float* __restrict__ Ad,
                            float* __restrict__ esrc, float* __restrict__ edst,
                            int n) {
    constexpr int LDK = K + 16;
    __shared__ __align__(16) unsigned short a_sh[32 * LDK];
    int row0 = blockIdx.x * 32;
    int tid = threadIdx.x;

    constexpr int CH = 32 * K / 8;                  // 16B chunks
    for (int c = tid; c < CH; c += 256) {
        int r = c / (K / 8), kc = c % (K / 8);
        int row = row0 + r;
        uint4 pack;
        if (row < n) {
            if (SRC_F32) {
                const float* X = (const float*)Xv;
                float4 f0 = *reinterpret_cast<const float4*>(&X[(size_t)row * K + kc * 8]);
                float4 f1 = *reinterpret_cast<const float4*>(&X[(size_t)row * K + kc * 8 + 4]);
                pack.x = f2bf(f0.x) | ((unsigned)f2bf(f0.y) << 16);
                pack.y = f2bf(f0.z) | ((unsigned)f2bf(f0.w) << 16);
                pack.z = f2bf(f1.x) | ((unsigned)f2bf(f1.y) << 16);
                pack.w = f2bf(f1.z) | ((unsigned)f2bf(f1.w) << 16);
            } else {
                const uint4* X = (const uint4*)Xv;
                pack = X[((size_t)row * K + kc * 8) / 8];
            }
        } else {
            pack = make_uint4(0, 0, 0, 0);
        }
        *reinterpret_cast<uint4*>(&a_sh[r * LDK + kc * 8]) = pack;
    }
    __syncthreads();

    int lane = tid & 63;
    int w = tid >> 6;                              // wave == head
    int lr = lane & 15;
    int lk = (lane >> 4) * 8;

    f32x4 acc[2][4];
#pragma unroll
    for (int m = 0; m < 2; ++m)
#pragma unroll
        for (int nf = 0; nf < 4; ++nf) acc[m][nf] = (f32x4){0.f, 0.f, 0.f, 0.f};

    const unsigned short* wt = Wt + (size_t)(w * 64) * K;
#pragma unroll
    for (int ks = 0; ks < K / 32; ++ks) {
        bf16x8 a[2], b[4];
#pragma unroll
        for (int m = 0; m < 2; ++m)
            a[m] = *reinterpret_cast<const bf16x8*>(&a_sh[(16 * m + lr) * LDK + ks * 32 + lk]);
#pragma unroll
        for (int nf = 0; nf < 4; ++nf)
            b[nf] = *reinterpret_cast<const bf16x8*>(&wt[(size_t)(16 * nf + lr) * K + ks * 32 + lk]);
#pragma unroll
        for (int m = 0; m < 2; ++m)
#pragma unroll
            for (int nf = 0; nf < 4; ++nf)
                acc[m][nf] = __builtin_amdgcn_mfma_f32_16x16x32_bf16(a[m], b[nf], acc[m][nf], 0, 0, 0);
    }

    float as_v[4], ad_v[4];
#pragma unroll
    for (int nf = 0; nf < 4; ++nf) {
        as_v[nf] = As[w * 64 + 16 * nf + lr];
        ad_v[nf] = Ad[w * 64 + 16 * nf + lr];
    }
#pragma unroll
    for (int m = 0; m < 2; ++m) {
#pragma unroll
        for (int j = 0; j < 4; ++j) {
            int row_g = row0 + 16 * m + (lane >> 4) * 4 + j;
            bool ok = row_g < n;
#pragma unroll
            for (int nf = 0; nf < 4; ++nf) {
                if (ok) Hout[(size_t)row_g * HCOLS + w * 64 + 16 * nf + lr] = f2bf(acc[m][nf][j]);
            }
            float ps = acc[m][0][j] * as_v[0] + acc[m][1][j] * as_v[1] +
                       acc[m][2][j] * as_v[2] + acc[m][3][j] * as_v[3];
            float pd = acc[m][0][j] * ad_v[0] + acc[m][1][j] * ad_v[1] +
                       acc[m][2][j] * ad_v[2] + acc[m][3][j] * ad_v[3];
#pragma unroll
            for (int off = 1; off < 16; off <<= 1) {
                ps += __shfl_xor(ps, off, 64);
                pd += __shfl_xor(pd, off, 64);
            }
            if (lr == 0 && ok) {
                esrc[row_g * NHEAD + w] = ps;
                edst[row_g * NHEAD + w] = pd;
            }
        }
    }
}

// ---------------------------------------------------------------- fused segment-softmax + aggregation
// block = 4 nodes, wave = 1 node. Phase B: LDS-broadcast alpha/src + 4x-unrolled gather.
template <int MODE>  // 0: concat+bias+ELU -> bf16 xout, 1: head-mean+bias -> f32 out
__global__ void attn_agg_kernel(const unsigned short* __restrict__ h,
                                const float* __restrict__ esrc,
                                const float* __restrict__ edst,
                                const int* __restrict__ ei,
                                const int* __restrict__ rowptr,
                                const int* __restrict__ eidx,
                                const float* __restrict__ bias,
                                float* __restrict__ alpha,
                                void* __restrict__ xout,
                                int n, int E) {
    // per-wave LDS: alpha transposed head-major (stride 72 -> 4 group reads hit distinct banks) + src ids
    __shared__ __align__(16) float aT[4][NHEAD][72];
    __shared__ __align__(16) int   sArr[4][64];

    int wave = threadIdx.x >> 6;
    int lane = threadIdx.x & 63;
    int node = blockIdx.x * 4 + wave;
    if (node >= n) return;
    int s0 = rowptr[node], s1 = rowptr[node + 1];
    int deg = s1 - s0;
    float4 ed = *reinterpret_cast<const float4*>(&edst[node * NHEAD]);

    // ---------- phase A: segment softmax
    int i0 = s0 + lane;
    bool valid = i0 < s1;
    int e0 = 0, sv = 0;
    float4 lg0 = make_float4(-3.4e38f, -3.4e38f, -3.4e38f, -3.4e38f);
    if (valid) {
        e0 = eidx[i0];
        sv = (e0 < E) ? ei[e0] : (e0 - E);
        float4 es = *reinterpret_cast<const float4*>(&esrc[sv * NHEAD]);
        lg0.x = leaky(es.x + ed.x);
        lg0.y = leaky(es.y + ed.y);
        lg0.z = leaky(es.z + ed.z);
        lg0.w = leaky(es.w + ed.w);
    }
    float4 mx = lg0;
    for (int i = i0 + 64; i < s1; i += 64) {          // rare: deg > 64
        int e = eidx[i];
        int s = (e < E) ? ei[e] : (e - E);
        float4 es = *reinterpret_cast<const float4*>(&esrc[s * NHEAD]);
        mx.x = fmaxf(mx.x, leaky(es.x + ed.x));
        mx.y = fmaxf(mx.y, leaky(es.y + ed.y));
        mx.z = fmaxf(mx.z, leaky(es.z + ed.z));
        mx.w = fmaxf(mx.w, leaky(es.w + ed.w));
    }
#pragma unroll
    for (int off = 32; off; off >>= 1) {
        mx.x = fmaxf(mx.x, __shfl_xor(mx.x, off, 64));
        mx.y = fmaxf(mx.y, __shfl_xor(mx.y, off, 64));
        mx.z = fmaxf(mx.z, __shfl_xor(mx.z, off, 64));
        mx.w = fmaxf(mx.w, __shfl_xor(mx.w, off, 64));
    }
    float4 ex0 = make_float4(0.f, 0.f, 0.f, 0.f);
    if (valid) {
        ex0.x = __expf(lg0.x - mx.x);
        ex0.y = __expf(lg0.y - mx.y);
        ex0.z = __expf(lg0.z - mx.z);
        ex0.w = __expf(lg0.w - mx.w);
    }
    float4 sm = ex0;
    for (int i = i0 + 64; i < s1; i += 64) {
        int e = eidx[i];
        int s = (e < E) ? ei[e] : (e - E);
        float4 es = *reinterpret_cast<const float4*>(&esrc[s * NHEAD]);
        sm.x += __expf(leaky(es.x + ed.x) - mx.x);
        sm.y += __expf(leaky(es.y + ed.y) - mx.y);
        sm.z += __expf(leaky(es.z + ed.z) - mx.z);
        sm.w += __expf(leaky(es.w + ed.w) - mx.w);
    }
#pragma unroll
    for (int off = 32; off; off >>= 1) {
        sm.x += __shfl_xor(sm.x, off, 64);
        sm.y += __shfl_xor(sm.y, off, 64);
        sm.z += __shfl_xor(sm.z, off, 64);
        sm.w += __shfl_xor(sm.w, off, 64);
    }
    float4 inv = make_float4(1.f / sm.x, 1.f / sm.y, 1.f / sm.z, 1.f / sm.w);
    float4 al = make_float4(ex0.x * inv.x, ex0.y * inv.y, ex0.z * inv.z, ex0.w * inv.w);
    if (valid) *reinterpret_cast<float4*>(&alpha[(size_t)e0 * NHEAD]) = al;
    for (int i = i0 + 64; i < s1; i += 64) {
        int e = eidx[i];
        int s = (e < E) ? ei[e] : (e - E);
        float4 es = *reinterpret_cast<const float4*>(&esrc[s * NHEAD]);
        float4 av;
        av.x = __expf(leaky(es.x + ed.x) - mx.x) * inv.x;
        av.y = __expf(leaky(es.y + ed.y) - mx.y) * inv.y;
        av.z = __expf(leaky(es.z + ed.z) - mx.z) * inv.z;
        av.w = __expf(leaky(es.w + ed.w) - mx.w) * inv.w;
        *reinterpret_cast<float4*>(&alpha[(size_t)e * NHEAD]) = av;
    }
    bool big = deg > 64;
    if (big) __threadfence();

    // ---------- stash alpha (transposed) + src ids in LDS for broadcast
    aT[wave][0][lane] = valid ? al.x : 0.f;
    aT[wave][1][lane] = valid ? al.y : 0.f;
    aT[wave][2][lane] = valid ? al.z : 0.f;
    aT[wave][3][lane] = valid ? al.w : 0.f;
    sArr[wave][lane] = valid ? sv : 0;
    asm volatile("s_waitcnt lgkmcnt(0)" ::: "memory");   // same-wave LDS write->read
    __builtin_amdgcn_sched_barrier(0);

    // ---------- phase B: out[node] = sum_e alpha[e] * h[src(e)]   (h bf16, 512B/row)
    int head = lane >> 4;
    unsigned laneoff = (unsigned)(lane << 3);            // byte offset within row
    const char* hb = (const char*)h;
    float4 acc = make_float4(0.f, 0.f, 0.f, 0.f);
    int m = deg < 64 ? deg : 64;
    int m4 = (m + 3) & ~3;
    const float* aTp = &aT[wave][head][0];
    const int*   sp  = &sArr[wave][0];
    for (int j = 0; j < m4; j += 4) {
        float4 a4 = *reinterpret_cast<const float4*>(aTp + j);
        int4   s4 = *reinterpret_cast<const int4*>(sp + j);
        uint2 h0 = *reinterpret_cast<const uint2*>(hb + (((unsigned)s4.x << 9) + laneoff));
        uint2 h1 = *reinterpret_cast<const uint2*>(hb + (((unsigned)s4.y << 9) + laneoff));
        uint2 h2 = *reinterpret_cast<const uint2*>(hb + (((unsigned)s4.z << 9) + laneoff));
        uint2 h3 = *reinterpret_cast<const uint2*>(hb + (((unsigned)s4.w << 9) + laneoff));
        acc.x = fmaf(a4.x, bf2f((unsigned short)(h0.x & 0xffff)), acc.x);
        acc.y = fmaf(a4.x, bf2f((unsigned short)(h0.x >> 16)),    acc.y);
        acc.z = fmaf(a4.x, bf2f((unsigned short)(h0.y & 0xffff)), acc.z);
        acc.w = fmaf(a4.x, bf2f((unsigned short)(h0.y >> 16)),    acc.w);
        acc.x = fmaf(a4.y, bf2f((unsigned short)(h1.x & 0xffff)), acc.x);
        acc.y = fmaf(a4.y, bf2f((unsigned short)(h1.x >> 16)),    acc.y);
        acc.z = fmaf(a4.y, bf2f((unsigned short)(h1.y & 0xffff)), acc.z);
        acc.w = fmaf(a4.y, bf2f((unsigned short)(h1.y >> 16)),    acc.w);
        acc.x = fmaf(a4.z, bf2f((unsigned short)(h2.x & 0xffff)), acc.x);
        acc.y = fmaf(a4.z, bf2f((unsigned short)(h2.x >> 16)),    acc.y);
        acc.z = fmaf(a4.z, bf2f((unsigned short)(h2.y & 0xffff)), acc.z);
        acc.w = fmaf(a4.z, bf2f((unsigned short)(h2.y >> 16)),    acc.w);
        acc.x = fmaf(a4.w, bf2f((unsigned short)(h3.x & 0xffff)), acc.x);
        acc.y = fmaf(a4.w, bf2f((unsigned short)(h3.x >> 16)),    acc.y);
        acc.z = fmaf(a4.w, bf2f((unsigned short)(h3.y & 0xffff)), acc.z);
        acc.w = fmaf(a4.w, bf2f((unsigned short)(h3.y >> 16)),    acc.w);
    }
    if (big) {                            // rare slow path: edges beyond 64
        for (int i = s0 + 64; i < s1; ++i) {
            int e = eidx[i];
            int s = (e < E) ? ei[e] : (e - E);
            float4 av = *reinterpret_cast<const float4*>(&alpha[(size_t)e * NHEAD]);
            float a = (head & 2) ? ((head & 1) ? av.w : av.z) : ((head & 1) ? av.y : av.x);
            uint2 hv = *reinterpret_cast<const uint2*>(hb + (((unsigned)s << 9) + laneoff));
            acc.x = fmaf(a, bf2f((unsigned short)(hv.x & 0xffff)), acc.x);
            acc.y = fmaf(a, bf2f((unsigned short)(hv.x >> 16)),    acc.y);
            acc.z = fmaf(a, bf2f((unsigned short)(hv.y & 0xffff)), acc.z);
            acc.w = fmaf(a, bf2f((unsigned short)(hv.y >> 16)),    acc.w);
        }
    }
    if (MODE == 0) {
        float4 bv = *reinterpret_cast<const float4*>(&bias[lane << 2]);
        float4 v;
        v.x = acc.x + bv.x; v.y = acc.y + bv.y; v.z = acc.z + bv.z; v.w = acc.w + bv.w;
        v.x = v.x > 0.f ? v.x : expm1f(v.x);
        v.y = v.y > 0.f ? v.y : expm1f(v.y);
        v.z = v.z > 0.f ? v.z : expm1f(v.z);
        v.w = v.w > 0.f ? v.w : expm1f(v.w);
        ushort4 o;
        o.x = f2bf(v.x); o.y = f2bf(v.y); o.z = f2bf(v.z); o.w = f2bf(v.w);
        *reinterpret_cast<ushort4*>(&((unsigned short*)xout)[(size_t)node * HCOLS + (lane << 2)]) = o;
    } else {
        acc.x += __shfl_xor(acc.x, 16, 64); acc.x += __shfl_xor(acc.x, 32, 64);
        acc.y += __shfl_xor(acc.y, 16, 64); acc.y += __shfl_xor(acc.y, 32, 64);
        acc.z += __shfl_xor(acc.z, 16, 64); acc.z += __shfl_xor(acc.z, 32, 64);
        acc.w += __shfl_xor(acc.w, 16, 64); acc.w += __shfl_xor(acc.w, 32, 64);
        if (lane < 16) {
            float4 bv = *reinterpret_cast<const float4*>(&bias[lane << 2]);
            float4 v;
            v.x = acc.x * 0.25f + bv.x;
            v.y = acc.y * 0.25f + bv.y;
            v.z = acc.z * 0.25f + bv.z;
            v.w = acc.w * 0.25f + bv.w;
            *reinterpret_cast<float4*>(&((float*)xout)[(size_t)node * CDIM + (lane << 2)]) = v;
        }
    }
}

// ---------------------------------------------------------------- launch
extern "C" void kernel_launch(void* const* d_in, const int* in_sizes, int n_in,
                              void* d_out, int out_size, void* d_ws, size_t ws_size,
                              hipStream_t stream) {
    const float* x   = (const float*)d_in[0];
    const int*   ei  = (const int*)d_in[1];
    const float* W0  = (const float*)d_in[2];
    const float* as0 = (const float*)d_in[3];
    const float* ad0 = (const float*)d_in[4];
    const float* b0  = (const float*)d_in[5];
    const float* W1  = (const float*)d_in[6];
    const float* as1 = (const float*)d_in[7];
    const float* ad1 = (const float*)d_in[8];
    const float* b1  = (const float*)d_in[9];
    const float* W2  = (const float*)d_in[10];
    const float* as2 = (const float*)d_in[11];
    const float* ad2 = (const float*)d_in[12];
    const float* b2  = (const float*)d_in[13];

    const int N  = in_sizes[0] / 128;
    const int E  = in_sizes[1] / 2;
    const int Ep = E + N;

    float* out = (float*)d_out;
    float* a0  = out + (size_t)N * CDIM;
    float* a1  = a0 + (size_t)Ep * NHEAD;
    float* a2  = a1 + (size_t)Ep * NHEAD;

    char* wp = (char*)d_ws;
    auto carve = [&](size_t bytes) {
        char* p = wp;
        wp += (bytes + 255) & ~(size_t)255;
        return (void*)p;
    };
    unsigned short* hbuf = (unsigned short*)carve((size_t)N * HCOLS * 2);   // bf16
    unsigned short* xbuf = (unsigned short*)carve((size_t)N * HCOLS * 2);   // bf16
    float* esrc   = (float*)carve((size_t)N * NHEAD * 4);
    float* edst   = (float*)carve((size_t)N * NHEAD * 4);
    int*   deg    = (int*)carve((size_t)N * 4);
    int*   rowptr = (int*)carve((size_t)(N + 1) * 4);
    int*   cursor = (int*)carve((size_t)N * 4);
    int*   eidx   = (int*)carve((size_t)Ep * 4);
    unsigned short* Wt0 = (unsigned short*)carve((size_t)HCOLS * 128 * 2);
    unsigned short* Wt1 = (unsigned short*)carve((size_t)HCOLS * HCOLS * 2);
    unsigned short* Wt2 = (unsigned short*)carve((size_t)HCOLS * HCOLS * 2);

    // CSR by dst (graph identical for all layers)
    hipMemsetAsync(deg, 0, (size_t)N * 4, stream);
    deg_kernel<<<(Ep + 255) / 256, 256, 0, stream>>>(ei, deg, E, Ep);
    scan_kernel<<<1, 1024, 0, stream>>>(deg, rowptr, cursor, N);
    fill_kernel<<<(Ep + 255) / 256, 256, 0, stream>>>(ei, cursor, eidx, E, Ep);

    // W -> bf16 transposed
    wconv_kernel<<<dim3(8, 4), 256, 0, stream>>>(W0, Wt0, 128);
    wconv_kernel<<<dim3(8, 8), 256, 0, stream>>>(W1, Wt1, 256);
    wconv_kernel<<<dim3(8, 8), 256, 0, stream>>>(W2, Wt2, 256);

    int gemm_grid = (N + 31) / 32;
    int agg_grid  = (N + 3) / 4;

    // ---- layer 0 (K = 128, fp32 source)
    gemm_kernel<128, true><<<gemm_grid, 256, 0, stream>>>(x, Wt0, hbuf, as0, ad0, esrc, edst, N);
    attn_agg_kernel<0><<<agg_grid, 256, 0, stream>>>(hbuf, esrc, edst, ei, rowptr, eidx, b0, a0, xbuf, N, E);

    // ---- layer 1 (K = 256, bf16 source)
    gemm_kernel<256, false><<<gemm_grid, 256, 0, stream>>>(xbuf, Wt1, hbuf, as1, ad1, esrc, edst, N);
    attn_agg_kernel<0><<<agg_grid, 256, 0, stream>>>(hbuf, esrc, edst, ei, rowptr, eidx, b1, a1, xbuf, N, E);

    // ---- layer 2 (K = 256, bf16 source, mean over heads)
    gemm_kernel<256, false><<<gemm_grid, 256, 0, stream>>>(xbuf, Wt2, hbuf, as2, ad2, esrc, edst, N);
    attn_agg_kernel<1><<<agg_grid, 256, 0, stream>>>(hbuf, esrc, edst, ei, rowptr, eidx, b2, a2, out, N, E);
}

// Round 5
// 233.548 us; speedup vs baseline: 3.2429x; 1.0453x over previous
//
#include <hip/hip_runtime.h>
#include <hip/hip_bf16.h>
#include <math.h>

#define HCOLS 256          // H * C = 4 * 64, hidden width for all layers
#define NHEAD 4
#define CDIM  64
#define NEG_SLOPE 0.2f

typedef __attribute__((ext_vector_type(8))) short bf16x8;
typedef __attribute__((ext_vector_type(4))) float f32x4;

__device__ __forceinline__ float leaky(float v) { return v > 0.f ? v : v * NEG_SLOPE; }
__device__ __forceinline__ unsigned short f2bf(float f) {      // RNE
    unsigned u = __float_as_uint(f);
    u += 0x7fff + ((u >> 16) & 1);
    return (unsigned short)(u >> 16);
}

// expand uint4 (8 bf16) and fma into acc[8] with scalar a
__device__ __forceinline__ void fma8(float* acc, uint4 hv, float a) {
    acc[0] = fmaf(a, __uint_as_float(hv.x << 16),          acc[0]);
    acc[1] = fmaf(a, __uint_as_float(hv.x & 0xffff0000u),  acc[1]);
    acc[2] = fmaf(a, __uint_as_float(hv.y << 16),          acc[2]);
    acc[3] = fmaf(a, __uint_as_float(hv.y & 0xffff0000u),  acc[3]);
    acc[4] = fmaf(a, __uint_as_float(hv.z << 16),          acc[4]);
    acc[5] = fmaf(a, __uint_as_float(hv.z & 0xffff0000u),  acc[5]);
    acc[6] = fmaf(a, __uint_as_float(hv.w << 16),          acc[6]);
    acc[7] = fmaf(a, __uint_as_float(hv.w & 0xffff0000u),  acc[7]);
}

// ---------------------------------------------------------------- CSR build
__global__ void zero_deg_kernel(int* __restrict__ deg, int n) {
    int i = blockIdx.x * 256 + threadIdx.x;
    if (i < n) deg[i] = 0;
}

__global__ void deg_kernel(const int* __restrict__ ei, int* __restrict__ deg,
                           int E, int Ep) {
    int e = blockIdx.x * 256 + threadIdx.x;
    if (e >= Ep) return;
    int d = (e < E) ? ei[E + e] : (e - E);
    atomicAdd(&deg[d], 1);
}

// 1024 threads, thread owns CH contiguous elems: local sum -> shuffle scan -> write-back
__global__ void scan_kernel(const int* __restrict__ deg, int* __restrict__ rowptr,
                            int* __restrict__ cursor, int n) {
    __shared__ int wsum[16];
    int tid = threadIdx.x;
    int lane = tid & 63, w = tid >> 6;
    int CH = (n + 1023) >> 10;
    int base = tid * CH;
    int s = 0;
    for (int k = 0; k < CH; ++k) {
        int i = base + k;
        s += (i < n) ? deg[i] : 0;
    }
    int incl = s;
#pragma unroll
    for (int d = 1; d < 64; d <<= 1) {
        int t = __shfl_up(incl, d, 64);
        if (lane >= d) incl += t;
    }
    if (lane == 63) wsum[w] = incl;
    __syncthreads();
    if (w == 0) {
        int v = (lane < 16) ? wsum[lane] : 0;
#pragma unroll
        for (int d = 1; d < 16; d <<= 1) {
            int t = __shfl_up(v, d, 64);
            if (lane >= d) v += t;
        }
        if (lane < 16) wsum[lane] = v;
    }
    __syncthreads();
    int woff = (w == 0) ? 0 : wsum[w - 1];
    int run = woff + incl - s;
    for (int k = 0; k < CH; ++k) {
        int i = base + k;
        if (i < n) { rowptr[i] = run; cursor[i] = run; run += deg[i]; }
    }
    if (tid == 1023) rowptr[n] = run;
}

__global__ void fill_kernel(const int* __restrict__ ei, int* __restrict__ cursor,
                            int* __restrict__ eidx, int E, int Ep) {
    int e = blockIdx.x * 256 + threadIdx.x;
    if (e >= Ep) return;
    int d = (e < E) ? ei[E + e] : (e - E);
    int pos = atomicAdd(&cursor[d], 1);
    eidx[pos] = e;
}

// ---------------------------------------------------------------- W transpose+convert (all 3 in one launch)
__global__ void wconv_kernel(const float* __restrict__ W0, const float* __restrict__ W1,
                             const float* __restrict__ W2,
                             unsigned short* __restrict__ Wt0, unsigned short* __restrict__ Wt1,
                             unsigned short* __restrict__ Wt2) {
    __shared__ float t[32][33];
    int z = blockIdx.z;
    const float* W = (z == 0) ? W0 : (z == 1) ? W1 : W2;
    unsigned short* Wt = (z == 0) ? Wt0 : (z == 1) ? Wt1 : Wt2;
    int K = (z == 0) ? 128 : 256;
    if (blockIdx.y * 32 >= K) return;
    int bx = blockIdx.x;                 // col tile (over 256)
    int by = blockIdx.y;                 // k tile
    int tx = threadIdx.x & 31, ty = threadIdx.x >> 5;   // 32 x 8
#pragma unroll
    for (int i = 0; i < 32; i += 8)
        t[ty + i][tx] = W[(by * 32 + ty + i) * HCOLS + bx * 32 + tx];
    __syncthreads();
#pragma unroll
    for (int i = 0; i < 32; i += 8)
        Wt[(size_t)(bx * 32 + ty + i) * K + by * 32 + tx] = f2bf(t[tx][ty + i]);
}

// ---------------------------------------------------------------- MFMA GEMM  h = X @ W (+ fused attn coefs)
// block: 256 thr = 4 waves; 32 rows x 256 cols. wave w -> cols [64w,64w+64) == head w.
template <int K, bool SRC_F32>
__global__ void gemm_kernel(const void* __restrict__ Xv, const unsigned short* __restrict__ Wt,
                            unsigned short* __restrict__ Hout,
                            const float* __restrict__ As, const float* __restrict__ Ad,
                            float* __restrict__ esrc, float* __restrict__ edst,
                            int n) {
    constexpr int LDK = K + 16;
    __shared__ __align__(16) unsigned short a_sh[32 * LDK];
    int row0 = blockIdx.x * 32;
    int tid = threadIdx.x;

    constexpr int CH = 32 * K / 8;                  // 16B chunks
    for (int c = tid; c < CH; c += 256) {
        int r = c / (K / 8), kc = c % (K / 8);
        int row = row0 + r;
        uint4 pack;
        if (row < n) {
            if (SRC_F32) {
                const float* X = (const float*)Xv;
                float4 f0 = *reinterpret_cast<const float4*>(&X[(size_t)row * K + kc * 8]);
                float4 f1 = *reinterpret_cast<const float4*>(&X[(size_t)row * K + kc * 8 + 4]);
                pack.x = f2bf(f0.x) | ((unsigned)f2bf(f0.y) << 16);
                pack.y = f2bf(f0.z) | ((unsigned)f2bf(f0.w) << 16);
                pack.z = f2bf(f1.x) | ((unsigned)f2bf(f1.y) << 16);
                pack.w = f2bf(f1.z) | ((unsigned)f2bf(f1.w) << 16);
            } else {
                const uint4* X = (const uint4*)Xv;
                pack = X[((size_t)row * K + kc * 8) / 8];
            }
        } else {
            pack = make_uint4(0, 0, 0, 0);
        }
        *reinterpret_cast<uint4*>(&a_sh[r * LDK + kc * 8]) = pack;
    }
    __syncthreads();

    int lane = tid & 63;
    int w = tid >> 6;                              // wave == head
    int lr = lane & 15;
    int lk = (lane >> 4) * 8;

    f32x4 acc[2][4];
#pragma unroll
    for (int m = 0; m < 2; ++m)
#pragma unroll
        for (int nf = 0; nf < 4; ++nf) acc[m][nf] = (f32x4){0.f, 0.f, 0.f, 0.f};

    const unsigned short* wt = Wt + (size_t)(w * 64) * K;
#pragma unroll
    for (int ks = 0; ks < K / 32; ++ks) {
        bf16x8 a[2], b[4];
#pragma unroll
        for (int m = 0; m < 2; ++m)
            a[m] = *reinterpret_cast<const bf16x8*>(&a_sh[(16 * m + lr) * LDK + ks * 32 + lk]);
#pragma unroll
        for (int nf = 0; nf < 4; ++nf)
            b[nf] = *reinterpret_cast<const bf16x8*>(&wt[(size_t)(16 * nf + lr) * K + ks * 32 + lk]);
#pragma unroll
        for (int m = 0; m < 2; ++m)
#pragma unroll
            for (int nf = 0; nf < 4; ++nf)
                acc[m][nf] = __builtin_amdgcn_mfma_f32_16x16x32_bf16(a[m], b[nf], acc[m][nf], 0, 0, 0);
    }

    float as_v[4], ad_v[4];
#pragma unroll
    for (int nf = 0; nf < 4; ++nf) {
        as_v[nf] = As[w * 64 + 16 * nf + lr];
        ad_v[nf] = Ad[w * 64 + 16 * nf + lr];
    }
#pragma unroll
    for (int m = 0; m < 2; ++m) {
#pragma unroll
        for (int j = 0; j < 4; ++j) {
            int row_g = row0 + 16 * m + (lane >> 4) * 4 + j;
            bool ok = row_g < n;
#pragma unroll
            for (int nf = 0; nf < 4; ++nf) {
                if (ok) Hout[(size_t)row_g * HCOLS + w * 64 + 16 * nf + lr] = f2bf(acc[m][nf][j]);
            }
            float ps = acc[m][0][j] * as_v[0] + acc[m][1][j] * as_v[1] +
                       acc[m][2][j] * as_v[2] + acc[m][3][j] * as_v[3];
            float pd = acc[m][0][j] * ad_v[0] + acc[m][1][j] * ad_v[1] +
                       acc[m][2][j] * ad_v[2] + acc[m][3][j] * ad_v[3];
#pragma unroll
            for (int off = 1; off < 16; off <<= 1) {
                ps += __shfl_xor(ps, off, 64);
                pd += __shfl_xor(pd, off, 64);
            }
            if (lr == 0 && ok) {
                esrc[row_g * NHEAD + w] = ps;
                edst[row_g * NHEAD + w] = pd;
            }
        }
    }
}

// ---------------------------------------------------------------- fused segment-softmax + aggregation
// 16 nodes/block (4/wave). Phase A: 16-lane group per node (dense lanes, 4-level reduce).
// Phase B: wave per node; lane-halves on 2 edges, uint4 (8ch) per lane, combine via shfl_xor(32).
template <int MODE>  // 0: concat+bias+ELU -> bf16 xout, 1: head-mean+bias -> f32 out
__launch_bounds__(256, 4)
__global__ void attn_agg_kernel(const unsigned short* __restrict__ h,
                                const float* __restrict__ esrc,
                                const float* __restrict__ edst,
                                const int* __restrict__ ei,
                                const int* __restrict__ rowptr,
                                const int* __restrict__ eidx,
                                const float* __restrict__ bias,
                                float* __restrict__ alpha,
                                void* __restrict__ xout,
                                int n, int E) {
    __shared__ __align__(16) float aT[16][64][NHEAD];   // [node][edge][head]
    __shared__ int sArr[16][64];

    int tid = threadIdx.x;
    int wave = tid >> 6, lane = tid & 63;
    int g = lane >> 4, t = lane & 15;
    int nodeblk = blockIdx.x * 16;
    int nidx = wave * 4 + g;
    int node = nodeblk + nidx;
    bool gvalid = node < n;
    int s0 = 0, s1 = 0;
    if (gvalid) { s0 = rowptr[node]; s1 = rowptr[node + 1]; }
    int deg = s1 - s0;
    float4 ed = make_float4(0.f, 0.f, 0.f, 0.f);
    if (gvalid) ed = *reinterpret_cast<const float4*>(&edst[node * NHEAD]);

    // ---------- phase A: segment softmax (16-lane group per node)
    const float NEGINF = -3.4e38f;
    float4 lgc[4]; int sc[4], ec[4];
    int degc = deg < 64 ? deg : 64;
    int nch = (degc + 15) >> 4;
    float4 mx = make_float4(NEGINF, NEGINF, NEGINF, NEGINF);
#pragma unroll
    for (int c = 0; c < 4; ++c) {
        sc[c] = 0; ec[c] = 0;
        lgc[c] = make_float4(NEGINF, NEGINF, NEGINF, NEGINF);
        if (c < nch) {
            int i = s0 + c * 16 + t;
            bool v = i < s1;
            int e = v ? eidx[i] : 0;
            int s = v ? ((e < E) ? ei[e] : (e - E)) : 0;
            sc[c] = s; ec[c] = e;
            if (v) {
                float4 es = *reinterpret_cast<const float4*>(&esrc[s * NHEAD]);
                lgc[c].x = leaky(es.x + ed.x);
                lgc[c].y = leaky(es.y + ed.y);
                lgc[c].z = leaky(es.z + ed.z);
                lgc[c].w = leaky(es.w + ed.w);
            }
            mx.x = fmaxf(mx.x, lgc[c].x);
            mx.y = fmaxf(mx.y, lgc[c].y);
            mx.z = fmaxf(mx.z, lgc[c].z);
            mx.w = fmaxf(mx.w, lgc[c].w);
        }
    }
    for (int i = s0 + 64 + t; i < s1; i += 16) {   // rare: deg > 64
        int e = eidx[i];
        int s = (e < E) ? ei[e] : (e - E);
        float4 es = *reinterpret_cast<const float4*>(&esrc[s * NHEAD]);
        mx.x = fmaxf(mx.x, leaky(es.x + ed.x));
        mx.y = fmaxf(mx.y, leaky(es.y + ed.y));
        mx.z = fmaxf(mx.z, leaky(es.z + ed.z));
        mx.w = fmaxf(mx.w, leaky(es.w + ed.w));
    }
#pragma unroll
    for (int off = 1; off < 16; off <<= 1) {
        mx.x = fmaxf(mx.x, __shfl_xor(mx.x, off, 64));
        mx.y = fmaxf(mx.y, __shfl_xor(mx.y, off, 64));
        mx.z = fmaxf(mx.z, __shfl_xor(mx.z, off, 64));
        mx.w = fmaxf(mx.w, __shfl_xor(mx.w, off, 64));
    }
    float4 exc[4];
    float4 sm = make_float4(0.f, 0.f, 0.f, 0.f);
#pragma unroll
    for (int c = 0; c < 4; ++c) {
        exc[c] = make_float4(0.f, 0.f, 0.f, 0.f);
        if (c < nch) {
            exc[c].x = __expf(lgc[c].x - mx.x);   // invalid lanes: exp(-inf)=0
            exc[c].y = __expf(lgc[c].y - mx.y);
            exc[c].z = __expf(lgc[c].z - mx.z);
            exc[c].w = __expf(lgc[c].w - mx.w);
            sm.x += exc[c].x; sm.y += exc[c].y; sm.z += exc[c].z; sm.w += exc[c].w;
        }
    }
    for (int i = s0 + 64 + t; i < s1; i += 16) {   // rare
        int e = eidx[i];
        int s = (e < E) ? ei[e] : (e - E);
        float4 es = *reinterpret_cast<const float4*>(&esrc[s * NHEAD]);
        sm.x += __expf(leaky(es.x + ed.x) - mx.x);
        sm.y += __expf(leaky(es.y + ed.y) - mx.y);
        sm.z += __expf(leaky(es.z + ed.z) - mx.z);
        sm.w += __expf(leaky(es.w + ed.w) - mx.w);
    }
#pragma unroll
    for (int off = 1; off < 16; off <<= 1) {
        sm.x += __shfl_xor(sm.x, off, 64);
        sm.y += __shfl_xor(sm.y, off, 64);
        sm.z += __shfl_xor(sm.z, off, 64);
        sm.w += __shfl_xor(sm.w, off, 64);
    }
    float4 inv = make_float4(1.f / sm.x, 1.f / sm.y, 1.f / sm.z, 1.f / sm.w);
#pragma unroll
    for (int c = 0; c < 4; ++c) {
        if (c < nch) {
            float4 al4;
            al4.x = exc[c].x * inv.x; al4.y = exc[c].y * inv.y;
            al4.z = exc[c].z * inv.z; al4.w = exc[c].w * inv.w;
            int i = s0 + c * 16 + t;
            if (i < s1) *reinterpret_cast<float4*>(&alpha[(size_t)ec[c] * NHEAD]) = al4;
            *reinterpret_cast<float4*>(&aT[nidx][c * 16 + t][0]) = al4;  // 0 for invalid lanes
            sArr[nidx][c * 16 + t] = sc[c];
        }
    }
    for (int i = s0 + 64 + t; i < s1; i += 16) {   // rare
        int e = eidx[i];
        int s = (e < E) ? ei[e] : (e - E);
        float4 es = *reinterpret_cast<const float4*>(&esrc[s * NHEAD]);
        float4 av;
        av.x = __expf(leaky(es.x + ed.x) - mx.x) * inv.x;
        av.y = __expf(leaky(es.y + ed.y) - mx.y) * inv.y;
        av.z = __expf(leaky(es.z + ed.z) - mx.z) * inv.z;
        av.w = __expf(leaky(es.w + ed.w) - mx.w) * inv.w;
        *reinterpret_cast<float4*>(&alpha[(size_t)e * NHEAD]) = av;
    }
    if (__any(deg > 64)) __threadfence();

    asm volatile("s_waitcnt lgkmcnt(0)" ::: "memory");   // same-wave LDS write->read
    __builtin_amdgcn_sched_barrier(0);

    // ---------- phase B: out[node] = sum_e alpha[e] * h[src(e)]
    int half = lane >> 5;                 // which edge of the pair
    int q = lane & 31;                    // 16B slot within 512B row
    int head = q >> 3;
    unsigned byteoff = (unsigned)q * 16u;
    const char* hb = (const char*)h;

    for (int g2 = 0; g2 < 4; ++g2) {
        int nd = nodeblk + wave * 4 + g2;
        if (nd >= n) break;
        int t0 = rowptr[nd], t1 = rowptr[nd + 1];
        int dg = t1 - t0;
        int m = dg < 64 ? dg : 64;
        int m2 = (m + 1) & ~1;
        const float* ap = &aT[wave * 4 + g2][0][0] + head;
        const int* sp = &sArr[wave * 4 + g2][0];
        float acc[8];
#pragma unroll
        for (int k = 0; k < 8; ++k) acc[k] = 0.f;
        int j = 0;
        for (; j + 4 <= m2; j += 4) {
            int jA = j + half, jB = j + 2 + half;
            int sA = sp[jA], sB = sp[jB];
            float aA = ap[jA * NHEAD], aB = ap[jB * NHEAD];
            uint4 hA = *reinterpret_cast<const uint4*>(hb + (((unsigned)sA) << 9) + byteoff);
            uint4 hB = *reinterpret_cast<const uint4*>(hb + (((unsigned)sB) << 9) + byteoff);
            fma8(acc, hA, aA);
            fma8(acc, hB, aB);
        }
        for (; j < m2; j += 2) {
            int jA = j + half;
            int sA = sp[jA];
            float aA = ap[jA * NHEAD];
            uint4 hA = *reinterpret_cast<const uint4*>(hb + (((unsigned)sA) << 9) + byteoff);
            fma8(acc, hA, aA);
        }
        if (dg > 64) {                    // rare slow path
            for (int i = t0 + 64; i < t1; ++i) {
                if (half == 0) {
                    int e = eidx[i];
                    int s = (e < E) ? ei[e] : (e - E);
                    float a = alpha[(size_t)e * NHEAD + head];
                    uint4 hv = *reinterpret_cast<const uint4*>(hb + (((unsigned)s) << 9) + byteoff);
                    fma8(acc, hv, a);
                }
            }
        }
#pragma unroll
        for (int k = 0; k < 8; ++k) acc[k] += __shfl_xor(acc[k], 32, 64);

        if (MODE == 0) {
            if (half == 0) {
                float4 b0 = *reinterpret_cast<const float4*>(&bias[q * 8]);
                float4 b1 = *reinterpret_cast<const float4*>(&bias[q * 8 + 4]);
                float v0 = acc[0] + b0.x, v1 = acc[1] + b0.y, v2 = acc[2] + b0.z, v3 = acc[3] + b0.w;
                float v4 = acc[4] + b1.x, v5 = acc[5] + b1.y, v6 = acc[6] + b1.z, v7 = acc[7] + b1.w;
                v0 = v0 > 0.f ? v0 : expm1f(v0);
                v1 = v1 > 0.f ? v1 : expm1f(v1);
                v2 = v2 > 0.f ? v2 : expm1f(v2);
                v3 = v3 > 0.f ? v3 : expm1f(v3);
                v4 = v4 > 0.f ? v4 : expm1f(v4);
                v5 = v5 > 0.f ? v5 : expm1f(v5);
                v6 = v6 > 0.f ? v6 : expm1f(v6);
                v7 = v7 > 0.f ? v7 : expm1f(v7);
                uint4 o;
                o.x = (unsigned)f2bf(v0) | ((unsigned)f2bf(v1) << 16);
                o.y = (unsigned)f2bf(v2) | ((unsigned)f2bf(v3) << 16);
                o.z = (unsigned)f2bf(v4) | ((unsigned)f2bf(v5) << 16);
                o.w = (unsigned)f2bf(v6) | ((unsigned)f2bf(v7) << 16);
                *reinterpret_cast<uint4*>(&((unsigned short*)xout)[(size_t)nd * HCOLS + q * 8]) = o;
            }
        } else {
#pragma unroll
            for (int k = 0; k < 8; ++k) {
                acc[k] += __shfl_xor(acc[k], 8, 64);
                acc[k] += __shfl_xor(acc[k], 16, 64);
            }
            if (half == 0 && q < 8) {
                float* op = (float*)xout + (size_t)nd * CDIM + q * 8;
                float4 r0, r1;
                r0.x = acc[0] * 0.25f + bias[q * 8 + 0];
                r0.y = acc[1] * 0.25f + bias[q * 8 + 1];
                r0.z = acc[2] * 0.25f + bias[q * 8 + 2];
                r0.w = acc[3] * 0.25f + bias[q * 8 + 3];
                r1.x = acc[4] * 0.25f + bias[q * 8 + 4];
                r1.y = acc[5] * 0.25f + bias[q * 8 + 5];
                r1.z = acc[6] * 0.25f + bias[q * 8 + 6];
                r1.w = acc[7] * 0.25f + bias[q * 8 + 7];
                *reinterpret_cast<float4*>(op) = r0;
                *reinterpret_cast<float4*>(op + 4) = r1;
            }
        }
    }
}

// ---------------------------------------------------------------- launch
extern "C" void kernel_launch(void* const* d_in, const int* in_sizes, int n_in,
                              void* d_out, int out_size, void* d_ws, size_t ws_size,
                              hipStream_t stream) {
    const float* x   = (const float*)d_in[0];
    const int*   ei  = (const int*)d_in[1];
    const float* W0  = (const float*)d_in[2];
    const float* as0 = (const float*)d_in[3];
    const float* ad0 = (const float*)d_in[4];
    const float* b0  = (const float*)d_in[5];
    const float* W1  = (const float*)d_in[6];
    const float* as1 = (const float*)d_in[7];
    const float* ad1 = (const float*)d_in[8];
    const float* b1  = (const float*)d_in[9];
    const float* W2  = (const float*)d_in[10];
    const float* as2 = (const float*)d_in[11];
    const float* ad2 = (const float*)d_in[12];
    const float* b2  = (const float*)d_in[13];

    const int N  = in_sizes[0] / 128;
    const int E  = in_sizes[1] / 2;
    const int Ep = E + N;

    float* out = (float*)d_out;
    float* a0  = out + (size_t)N * CDIM;
    float* a1  = a0 + (size_t)Ep * NHEAD;
    float* a2  = a1 + (size_t)Ep * NHEAD;

    char* wp = (char*)d_ws;
    auto carve = [&](size_t bytes) {
        char* p = wp;
        wp += (bytes + 255) & ~(size_t)255;
        return (void*)p;
    };
    unsigned short* hbuf = (unsigned short*)carve((size_t)N * HCOLS * 2);   // bf16
    unsigned short* xbuf = (unsigned short*)carve((size_t)N * HCOLS * 2);   // bf16
    float* esrc   = (float*)carve((size_t)N * NHEAD * 4);
    float* edst   = (float*)carve((size_t)N * NHEAD * 4);
    int*   deg    = (int*)carve((size_t)N * 4);
    int*   rowptr = (int*)carve((size_t)(N + 1) * 4);
    int*   cursor = (int*)carve((size_t)N * 4);
    int*   eidx   = (int*)carve((size_t)Ep * 4);
    unsigned short* Wt0 = (unsigned short*)carve((size_t)HCOLS * 128 * 2);
    unsigned short* Wt1 = (unsigned short*)carve((size_t)HCOLS * HCOLS * 2);
    unsigned short* Wt2 = (unsigned short*)carve((size_t)HCOLS * HCOLS * 2);

    // CSR by dst (graph identical for all layers)
    zero_deg_kernel<<<(N + 255) / 256, 256, 0, stream>>>(deg, N);
    deg_kernel<<<(Ep + 255) / 256, 256, 0, stream>>>(ei, deg, E, Ep);
    scan_kernel<<<1, 1024, 0, stream>>>(deg, rowptr, cursor, N);
    fill_kernel<<<(Ep + 255) / 256, 256, 0, stream>>>(ei, cursor, eidx, E, Ep);

    // W -> bf16 transposed (single launch)
    wconv_kernel<<<dim3(8, 8, 3), 256, 0, stream>>>(W0, W1, W2, Wt0, Wt1, Wt2);

    int gemm_grid = (N + 31) / 32;
    int agg_grid  = (N + 15) / 16;

    // ---- layer 0 (K = 128, fp32 source)
    gemm_kernel<128, true><<<gemm_grid, 256, 0, stream>>>(x, Wt0, hbuf, as0, ad0, esrc, edst, N);
    attn_agg_kernel<0><<<agg_grid, 256, 0, stream>>>(hbuf, esrc, edst, ei, rowptr, eidx, b0, a0, xbuf, N, E);

    // ---- layer 1 (K = 256, bf16 source)
    gemm_kernel<256, false><<<gemm_grid, 256, 0, stream>>>(xbuf, Wt1, hbuf, as1, ad1, esrc, edst, N);
    attn_agg_kernel<0><<<agg_grid, 256, 0, stream>>>(hbuf, esrc, edst, ei, rowptr, eidx, b1, a1, xbuf, N, E);

    // ---- layer 2 (K = 256, bf16 source, mean over heads)
    gemm_kernel<256, false><<<gemm_grid, 256, 0, stream>>>(xbuf, Wt2, hbuf, as2, ad2, esrc, edst, N);
    attn_agg_kernel<1><<<agg_grid, 256, 0, stream>>>(hbuf, esrc, edst, ei, rowptr, eidx, b2, a2, out, N, E);
}